// Round 4
// baseline (915.908 us; speedup 1.0000x reference)
//
#include <hip/hip_runtime.h>

#define F_IN 512
#define F_HID 16
#define F_OUT 7
#define BUCKET 128          // nodes per bucket
#define LB 7                // log2(BUCKET)
#define TRASH 128           // dl value for sentinel pad edges in bedges
#define PADV 128            // packed sentinel: src=0, dl=TRASH
#define CHUNK 4096          // edges per partition block
#define MAXNB 1024          // max buckets supported by scans

// GEMM1 tiling
#define RPB 256             // rows per block
#define KC 32               // staged k-chunk
#define KHALF 256           // K range per split block (F_IN / KSPLIT)
#define LSTRIDE 33          // LDS row stride (pad: 2-way bank aliasing = free)

typedef int   int4v   __attribute__((ext_vector_type(4)));
typedef float float2v __attribute__((ext_vector_type(2)));
typedef float float4v __attribute__((ext_vector_type(4)));
typedef unsigned int uint4v __attribute__((ext_vector_type(4)));

static __device__ __forceinline__ unsigned short f2bf(float f) {   // RNE
    unsigned int u = __float_as_uint(f);
    u += 0x7FFFu + ((u >> 16) & 1u);
    return (unsigned short)(u >> 16);
}
static __device__ __forceinline__ float bf2f(unsigned short s) {
    return __uint_as_float((unsigned int)s << 16);
}

// ---------------- hist: per-block LDS histogram -> coalesced global row ----------------
// No global atomics. bh[blk*NBA + i] = count of bucket i in this block's chunk.
__global__ __launch_bounds__(256) void k_hist(const int* __restrict__ dst,
                                              int* __restrict__ bh, int E, int NB, int NBA) {
    __shared__ int hist[MAXNB];
    int t = threadIdx.x, blk = blockIdx.x;
    for (int i = t; i < NB; i += 256) hist[i] = 0;
    __syncthreads();
    int base = blk * CHUNK;
#pragma unroll
    for (int it = 0; it < CHUNK / 1024; ++it) {
        int e = base + (it * 256 + t) * 4;
        if (e < E) {                                   // E % 4 == 0 -> whole quad valid
            int4v d4 = __builtin_nontemporal_load((const int4v*)(dst + e));
            atomicAdd(&hist[d4.x >> LB], 1);
            atomicAdd(&hist[d4.y >> LB], 1);
            atomicAdd(&hist[d4.z >> LB], 1);
            atomicAdd(&hist[d4.w >> LB], 1);
        }
    }
    __syncthreads();
    int* row = bh + (size_t)blk * NBA;
    for (int i = t; i < NB; i += 256) row[i] = hist[i];
}

// ---------------- column scan: bh column i -> exclusive prefix over blocks ----------------
// One wave per bucket. Also emits true bucket counts.
__global__ __launch_bounds__(64) void k_cscan(int* __restrict__ bh, int* __restrict__ bucket_cnt,
                                              int PBLK, int NBA) {
    int i = blockIdx.x;            // bucket
    int lane = threadIdx.x;        // 0..63
    int carry = 0;
    for (int k0 = 0; k0 < PBLK; k0 += 64) {
        int b = k0 + lane;
        int v = (b < PBLK) ? bh[(size_t)b * NBA + i] : 0;
        int s = v;
#pragma unroll
        for (int off = 1; off < 64; off <<= 1) {
            int u = __shfl_up(s, off);
            if (lane >= off) s += u;
        }
        if (b < PBLK) bh[(size_t)b * NBA + i] = carry + s - v;   // exclusive prefix
        carry += __shfl(s, 63);
    }
    if (lane == 0) bucket_cnt[i] = carry;
}

// ---- scan 1: exclusive scan of 4-aligned bucket counts + sentinel pad tails ----
__global__ void k_bscan1(const int* __restrict__ bucket_cnt, int* __restrict__ bucket_base,
                         int* __restrict__ bedges, int NB) {
    __shared__ int sm[MAXNB];
    int t = threadIdx.x;                       // 1024 threads
    int c = (t < NB) ? bucket_cnt[t] : 0;
    int ca = (c + 3) & ~3;
    sm[t] = ca;
    __syncthreads();
    for (int off = 1; off < MAXNB; off <<= 1) {
        int v = sm[t];
        int add = (t >= off) ? sm[t - off] : 0;
        __syncthreads();
        sm[t] = v + add;
        __syncthreads();
    }
    if (t < NB) {
        int base = sm[t] - ca;
        bucket_base[t] = base;
        for (int i = c; i < ca; ++i) bedges[base + i] = PADV;
    }
}

// ------- place: block rank-and-reorder, then run-coalesced write-out (low write-amp) -------
__global__ __launch_bounds__(256) void k_place3(
        const int* __restrict__ src, const int* __restrict__ dst,
        const int* __restrict__ bucket_base, const int* __restrict__ bh,
        int* __restrict__ bedges, int E, int NB, int NBA) {
    __shared__ int h[MAXNB];                   // hist -> exclusive cursor
    __shared__ int s[MAXNB];                   // inclusive scan -> dbase
    __shared__ int sedge[CHUNK];               // 16 KB reordered packed edges
    __shared__ unsigned short sbkt[CHUNK];     // 8 KB bucket id per slot
    int t = threadIdx.x, blk = blockIdx.x;
    for (int i = t; i < MAXNB; i += 256) h[i] = 0;
    __syncthreads();
    int base = blk * CHUNK;
    int4v d4[4], s4[4];
#pragma unroll
    for (int it = 0; it < 4; ++it) {
        int e = base + (it * 256 + t) * 4;
        if (e < E) {                           // E % 4 == 0 -> whole quad valid
            d4[it] = __builtin_nontemporal_load((const int4v*)(dst + e));
            s4[it] = __builtin_nontemporal_load((const int4v*)(src + e));
        } else {
            int sent = NB << LB;               // sentinel bucket NB (skipped at write-out)
            d4[it].x = sent; d4[it].y = sent; d4[it].z = sent; d4[it].w = sent;
            s4[it].x = 0;    s4[it].y = 0;    s4[it].z = 0;    s4[it].w = 0;
        }
        atomicAdd(&h[d4[it].x >> LB], 1);
        atomicAdd(&h[d4[it].y >> LB], 1);
        atomicAdd(&h[d4[it].z >> LB], 1);
        atomicAdd(&h[d4[it].w >> LB], 1);
    }
    __syncthreads();
    for (int i = t; i < MAXNB; i += 256) s[i] = h[i];
    __syncthreads();
    // inclusive Hillis-Steele scan of s[0..1023], 256 threads x 4
    for (int off = 1; off < MAXNB; off <<= 1) {
        int v[4];
#pragma unroll
        for (int j = 0; j < 4; ++j) {
            int i = t + j * 256;
            v[j] = s[i] + ((i >= off) ? s[i - off] : 0);
        }
        __syncthreads();
#pragma unroll
        for (int j = 0; j < 4; ++j) s[t + j * 256] = v[j];
        __syncthreads();
    }
    // h := exclusive prefix (rank cursor); s := dbase = global_start - local_excl
    const int* row = bh + (size_t)blk * NBA;
    for (int i = t; i < MAXNB; i += 256) {
        int excl = s[i] - h[i];
        h[i] = excl;
        s[i] = (i < NB) ? (bucket_base[i] + row[i] - excl) : 0;
    }
    __syncthreads();
    // rank & reorder into LDS
#pragma unroll
    for (int it = 0; it < 4; ++it) {
        int d, sv, b, p;
        d = d4[it].x; sv = s4[it].x; b = d >> LB; p = atomicAdd(&h[b], 1);
        sedge[p] = (sv << 8) | (d & (BUCKET - 1)); sbkt[p] = (unsigned short)b;
        d = d4[it].y; sv = s4[it].y; b = d >> LB; p = atomicAdd(&h[b], 1);
        sedge[p] = (sv << 8) | (d & (BUCKET - 1)); sbkt[p] = (unsigned short)b;
        d = d4[it].z; sv = s4[it].z; b = d >> LB; p = atomicAdd(&h[b], 1);
        sedge[p] = (sv << 8) | (d & (BUCKET - 1)); sbkt[p] = (unsigned short)b;
        d = d4[it].w; sv = s4[it].w; b = d >> LB; p = atomicAdd(&h[b], 1);
        sedge[p] = (sv << 8) | (d & (BUCKET - 1)); sbkt[p] = (unsigned short)b;
    }
    __syncthreads();
    // write-out: consecutive j in a bucket run -> consecutive dest (coalesced bursts)
    for (int j = t; j < CHUNK; j += 256) {
        int b = sbkt[j];
        if (b < NB)
            __builtin_nontemporal_store(sedge[j], bedges + s[b] + j);
    }
}

// ---- per-bucket degree hist -> dinv only (no offsets/scan; CSR sort eliminated) ----
__global__ void k_pcount2(const int* __restrict__ bucket_base, const int* __restrict__ bucket_cnt,
                          const int* __restrict__ bedges, float* __restrict__ dinv, int n) {
    __shared__ int cnt[TRASH + 8];             // bins 0..128 (128 = sentinel trash)
    int b = blockIdx.x, t = threadIdx.x;       // 256 threads
    for (int i = t; i < TRASH + 8; i += 256) cnt[i] = 0;
    __syncthreads();
    int base = bucket_base[b], ne = bucket_cnt[b];
    int nqq = (ne + 3) >> 2;
    for (int qi = t; qi < nqq; qi += 256) {
        int4v q = __builtin_nontemporal_load((const int4v*)(bedges + base + (qi << 2)));
        atomicAdd(&cnt[q.x & 255], 1);
        atomicAdd(&cnt[q.y & 255], 1);
        atomicAdd(&cnt[q.z & 255], 1);
        atomicAdd(&cnt[q.w & 255], 1);
    }
    __syncthreads();
    if (t < BUCKET) {
        int node = b * BUCKET + t;
        if (node < n) dinv[node] = rsqrtf((float)(cnt[t] + 1));   // +1 self-loop
    }
}

// -------- GEMM1: K-split x2, LDS-coalesced x staging, pk_fma accumulation --------
__global__ __launch_bounds__(256) void k_gemm1p(
        const float* __restrict__ x, const float* __restrict__ W,
        float* __restrict__ part, int n) {
    __shared__ float xs[RPB * LSTRIDE];        // 33792 B
    int b  = blockIdx.x >> 1;
    int ks = blockIdx.x & 1;
    int r0 = b * RPB;
    int t  = threadIdx.x;
    int r  = r0 + t;
    int kbase = ks * KHALF;

    float2v acc2[F_HID / 2];                   // float2 lanes -> v_pk_fma_f32
#pragma unroll
    for (int c = 0; c < F_HID / 2; ++c) acc2[c] = (float2v){0.0f, 0.0f};

    int lr0 = t >> 3;                           // 0..31 (stage row group)
    int c4  = t & 7;                            // 0..7  (float4 slot: 8 x 16B = 128B/row)

    for (int kc = 0; kc < KHALF; kc += KC) {
        __syncthreads();                        // xs reads of previous chunk done
#pragma unroll
        for (int j = 0; j < 8; ++j) {
            int lr = j * 32 + lr0;
            int gr = r0 + lr;
            float4v v = {0.0f, 0.0f, 0.0f, 0.0f};
            if (gr < n)
                v = *(const float4v*)(x + (size_t)gr * F_IN + kbase + kc + c4 * 4);
            float* d = xs + lr * LSTRIDE + c4 * 4;
            d[0] = v.x; d[1] = v.y; d[2] = v.z; d[3] = v.w;
        }
        __syncthreads();
        if (r < n) {
            const float* xrow = xs + t * LSTRIDE;
            const float2v* Wk2 = (const float2v*)(W + (size_t)(kbase + kc) * F_HID);
#pragma unroll
            for (int k = 0; k < KC; ++k) {
                float xv = xrow[k];
#pragma unroll
                for (int c2 = 0; c2 < F_HID / 2; ++c2)
                    acc2[c2] += xv * Wk2[k * (F_HID / 2) + c2];
            }
        }
    }
    if (r < n) {
        const float* a = (const float*)acc2;
        float4v* o = (float4v*)(part + ((size_t)ks * n + r) * F_HID);
        float4v w0 = {a[0],  a[1],  a[2],  a[3]};
        float4v w1 = {a[4],  a[5],  a[6],  a[7]};
        float4v w2 = {a[8],  a[9],  a[10], a[11]};
        float4v w3 = {a[12], a[13], a[14], a[15]};
        o[0] = w0; o[1] = w1; o[2] = w2; o[3] = w3;
    }
}

// -------- finalize GEMM1: sum K-split partials, scale by dinv, -> bf16 h1b --------
__global__ void k_fin1(const float* __restrict__ part, const float* __restrict__ dinv,
                       unsigned short* __restrict__ h1b, int n) {
    int tg = blockIdx.x * 256 + threadIdx.x;
    int r = tg >> 4, c = tg & 15;
    if (r > n) return;
    if (r == n) { h1b[(size_t)r * F_HID + c] = 0; return; }
    float v = part[(size_t)r * F_HID + c] + part[((size_t)n + r) * F_HID + c];
    h1b[(size_t)r * F_HID + c] = f2bf(dinv[r] * v);
}

// ---- agg layer 1 + relu/bias + GEMM2 fused: block-per-bucket, LDS fp32 accumulation ----
// 16 lanes per edge gather h1b row (32B) and ds_add_f32 into acc[dl][c]; epilogue does
// self-loop + dinv scale + relu+b1 + 16x7 GEMM via 16-lane shfl_xor butterfly -> h2b.
__global__ __launch_bounds__(256) void k_aggL1(
        const int* __restrict__ bucket_base, const int* __restrict__ bucket_cnt,
        const int* __restrict__ bedges, const unsigned short* __restrict__ h1b,
        const float* __restrict__ dinv, const float* __restrict__ b1,
        const float* __restrict__ W2, unsigned short* __restrict__ h2b, int n) {
    __shared__ float acc[BUCKET * F_HID];      // 8 KB; banks (dl*16+c)%32 -> ~2-way (free)
    int b = blockIdx.x, t = threadIdx.x;
    for (int i = t; i < BUCKET * F_HID; i += 256) acc[i] = 0.0f;
    __syncthreads();
    int base = bucket_base[b];
    int ne4 = (bucket_cnt[b] + 3) & ~3;        // padded count (pad entries dl=TRASH)
    int g = t >> 4, c = t & 15;                // 16 edge-groups x 16 lanes
    for (int e = g; e < ne4; e += 16) {
        int v = bedges[base + e];              // broadcast within group
        int dl = v & 255;
        if (dl < BUCKET) {
            float x = bf2f(h1b[((size_t)(unsigned)(v >> 8) << 4) + c]);
            unsafeAtomicAdd(&acc[dl * F_HID + c], x);
        }
    }
    __syncthreads();
    // epilogue: 16 node-groups x 16 lanes, 8 rounds
    for (int nd = g; nd < BUCKET; nd += 16) {
        int node = b * BUCKET + nd;
        if (node < n) {
            float dv = dinv[node];
            float a = acc[nd * F_HID + c] + bf2f(h1b[((size_t)node << 4) + c]);
            float z = fmaxf(dv * a + b1[c], 0.0f);
            float h[F_OUT];
#pragma unroll
            for (int o = 0; o < F_OUT; ++o) h[o] = z * W2[c * F_OUT + o];
#pragma unroll
            for (int sft = 8; sft >= 1; sft >>= 1)
#pragma unroll
                for (int o = 0; o < F_OUT; ++o) h[o] += __shfl_xor(h[o], sft, 16);
            if (c < 8) {
                unsigned short w = (c < F_OUT) ? f2bf(dv * h[c]) : (unsigned short)0;
                h2b[((size_t)node << 3) + c] = w;
            }
        }
    }
}

// ---- agg layer 2 + bias fused: block-per-bucket, LDS fp32 accumulation -> out ----
__global__ __launch_bounds__(256) void k_aggL2(
        const int* __restrict__ bucket_base, const int* __restrict__ bucket_cnt,
        const int* __restrict__ bedges, const unsigned short* __restrict__ h2b,
        const float* __restrict__ dinv, const float* __restrict__ b2,
        float* __restrict__ out, int n) {
    __shared__ float acc[BUCKET * 8];          // 4 KB; banks (dl*8+c)%32 -> ~2-way
    int b = blockIdx.x, t = threadIdx.x;
    for (int i = t; i < BUCKET * 8; i += 256) acc[i] = 0.0f;
    __syncthreads();
    int base = bucket_base[b];
    int ne4 = (bucket_cnt[b] + 3) & ~3;
    int g = t >> 3, c = t & 7;                 // 32 edge-groups x 8 lanes
    for (int e = g; e < ne4; e += 32) {
        int v = bedges[base + e];
        int dl = v & 255;
        if (dl < BUCKET) {
            float x = bf2f(h2b[((size_t)(unsigned)(v >> 8) << 3) + c]);
            unsafeAtomicAdd(&acc[dl * 8 + c], x);
        }
    }
    __syncthreads();
    for (int nd = g; nd < BUCKET; nd += 32) {
        int node = b * BUCKET + nd;
        if (node < n && c < F_OUT) {
            float a = acc[nd * 8 + c] + bf2f(h2b[((size_t)node << 3) + c]);
            out[(size_t)node * F_OUT + c] = dinv[node] * a + b2[c];
        }
    }
}

extern "C" void kernel_launch(void* const* d_in, const int* in_sizes, int n_in,
                              void* d_out, int out_size, void* d_ws, size_t ws_size,
                              hipStream_t stream) {
    const float* x  = (const float*)d_in[0];
    const int*   ei = (const int*)d_in[1];      // int64 in source but JAX x64 off -> int32
    const float* W1 = (const float*)d_in[2];
    const float* b1 = (const float*)d_in[3];
    const float* W2 = (const float*)d_in[4];
    const float* b2 = (const float*)d_in[5];
    float* out = (float*)d_out;

    const int n = in_sizes[0] / F_IN;       // 100000
    const int E = in_sizes[1] / 2;          // 3200000
    const int* src = ei;
    const int* dst = ei + E;

    const int NB = (n + BUCKET - 1) / BUCKET;   // 782 (<= MAXNB-1: sentinel bucket NB fits)
    const int NBA = (NB + 3) & ~3;              // 784 (16B-aligned rows)
    const int PBLK = (E + CHUNK - 1) / CHUNK;   // 782

    // workspace layout (16B-aligned sections)
    size_t Np = ((size_t)n + 3) & ~(size_t)3;
    char* ws = (char*)d_ws;
    int*   bucket_cnt   = (int*)ws;             ws += MAXNB * 4;
    int*   bucket_base  = (int*)ws;             ws += MAXNB * 4;
    int*   bh           = (int*)ws;             ws += (size_t)PBLK * NBA * 4;   // 2.45 MB
    float* dinv         = (float*)ws;           ws += Np * 4;
    int*   bedges       = (int*)ws;             ws += ((size_t)E + 4 * MAXNB) * 4;  // 12.8 MB, live to end
    float* part         = (float*)ws;           ws += (size_t)2 * Np * F_HID * 4;   // 12.8 MB
    unsigned short* h1b = (unsigned short*)ws;  ws += (Np + 4) * F_HID * 2;         // 3.2 MB
    unsigned short* h2b = (unsigned short*)ws;  ws += (Np + 4) * 8 * 2;             // 1.6 MB (h1b still live in aggL1)

    k_hist   <<<PBLK, 256, 0, stream>>>(dst, bh, E, NB, NBA);
    k_cscan  <<<NB, 64, 0, stream>>>(bh, bucket_cnt, PBLK, NBA);
    k_bscan1 <<<1, 1024, 0, stream>>>(bucket_cnt, bucket_base, bedges, NB);
    k_place3 <<<PBLK, 256, 0, stream>>>(src, dst, bucket_base, bh, bedges, E, NB, NBA);
    k_pcount2<<<NB, 256, 0, stream>>>(bucket_base, bucket_cnt, bedges, dinv, n);
    k_gemm1p <<<((n + RPB - 1) / RPB) * 2, 256, 0, stream>>>(x, W1, part, n);
    k_fin1   <<<((n + 1) * 16 + 255) / 256, 256, 0, stream>>>(part, dinv, h1b, n);
    k_aggL1  <<<NB, 256, 0, stream>>>(bucket_base, bucket_cnt, bedges, h1b, dinv, b1, W2, h2b, n);
    k_aggL2  <<<NB, 256, 0, stream>>>(bucket_base, bucket_cnt, bedges, h2b, dinv, b2, out, n);
}

// Round 5
// 915.495 us; speedup vs baseline: 1.0005x; 1.0005x over previous
//
#include <hip/hip_runtime.h>

#define F_IN 512
#define F_HID 16
#define F_OUT 7
#define BUCKET 128          // nodes per bucket
#define LB 7                // log2(BUCKET)
#define TRASH 128           // dl value for sentinel pad edges in bedges
#define PADV 128            // packed sentinel: src=0, dl=TRASH
#define CHUNK 4096          // edges per partition block
#define MAXNB 1024          // max buckets supported by scans
#define ATILE 4096          // staged edge tile in agg kernels (16 KB LDS)

// GEMM1 tiling
#define RPB 256             // rows per block
#define KC 32               // staged k-chunk
#define KHALF 256           // K range per split block (F_IN / KSPLIT)
#define LSTRIDE 33          // LDS row stride (pad: 2-way bank aliasing = free)

typedef int   int4v   __attribute__((ext_vector_type(4)));
typedef float float2v __attribute__((ext_vector_type(2)));
typedef float float4v __attribute__((ext_vector_type(4)));
typedef unsigned int uint4v __attribute__((ext_vector_type(4)));

static __device__ __forceinline__ unsigned short f2bf(float f) {   // RNE
    unsigned int u = __float_as_uint(f);
    u += 0x7FFFu + ((u >> 16) & 1u);
    return (unsigned short)(u >> 16);
}
static __device__ __forceinline__ float bf2f(unsigned short s) {
    return __uint_as_float((unsigned int)s << 16);
}

// ---------------- hist: per-block LDS histogram -> coalesced global row ----------------
__global__ __launch_bounds__(256) void k_hist(const int* __restrict__ dst,
                                              int* __restrict__ bh, int E, int NB, int NBA) {
    __shared__ int hist[MAXNB];
    int t = threadIdx.x, blk = blockIdx.x;
    for (int i = t; i < NB; i += 256) hist[i] = 0;
    __syncthreads();
    int base = blk * CHUNK;
#pragma unroll
    for (int it = 0; it < CHUNK / 1024; ++it) {
        int e = base + (it * 256 + t) * 4;
        if (e < E) {                                   // E % 4 == 0 -> whole quad valid
            int4v d4 = __builtin_nontemporal_load((const int4v*)(dst + e));
            atomicAdd(&hist[d4.x >> LB], 1);
            atomicAdd(&hist[d4.y >> LB], 1);
            atomicAdd(&hist[d4.z >> LB], 1);
            atomicAdd(&hist[d4.w >> LB], 1);
        }
    }
    __syncthreads();
    int* row = bh + (size_t)blk * NBA;
    for (int i = t; i < NB; i += 256) row[i] = hist[i];
}

// ---------------- column scan: bh column i -> exclusive prefix over blocks ----------------
__global__ __launch_bounds__(64) void k_cscan(int* __restrict__ bh, int* __restrict__ bucket_cnt,
                                              int PBLK, int NBA) {
    int i = blockIdx.x;            // bucket
    int lane = threadIdx.x;        // 0..63
    int carry = 0;
    for (int k0 = 0; k0 < PBLK; k0 += 64) {
        int b = k0 + lane;
        int v = (b < PBLK) ? bh[(size_t)b * NBA + i] : 0;
        int s = v;
#pragma unroll
        for (int off = 1; off < 64; off <<= 1) {
            int u = __shfl_up(s, off);
            if (lane >= off) s += u;
        }
        if (b < PBLK) bh[(size_t)b * NBA + i] = carry + s - v;   // exclusive prefix
        carry += __shfl(s, 63);
    }
    if (lane == 0) bucket_cnt[i] = carry;
}

// ---- scan 1: exclusive scan of 4-aligned bucket counts + sentinel pad tails ----
__global__ void k_bscan1(const int* __restrict__ bucket_cnt, int* __restrict__ bucket_base,
                         int* __restrict__ bedges, int NB) {
    __shared__ int sm[MAXNB];
    int t = threadIdx.x;                       // 1024 threads
    int c = (t < NB) ? bucket_cnt[t] : 0;
    int ca = (c + 3) & ~3;
    sm[t] = ca;
    __syncthreads();
    for (int off = 1; off < MAXNB; off <<= 1) {
        int v = sm[t];
        int add = (t >= off) ? sm[t - off] : 0;
        __syncthreads();
        sm[t] = v + add;
        __syncthreads();
    }
    if (t < NB) {
        int base = sm[t] - ca;
        bucket_base[t] = base;
        for (int i = c; i < ca; ++i) bedges[base + i] = PADV;
    }
}

// ------- place: block rank-and-reorder, then run-coalesced write-out (low write-amp) -------
__global__ __launch_bounds__(256) void k_place3(
        const int* __restrict__ src, const int* __restrict__ dst,
        const int* __restrict__ bucket_base, const int* __restrict__ bh,
        int* __restrict__ bedges, int E, int NB, int NBA) {
    __shared__ int h[MAXNB];                   // hist -> exclusive cursor
    __shared__ int s[MAXNB];                   // inclusive scan -> dbase
    __shared__ int sedge[CHUNK];               // 16 KB reordered packed edges
    __shared__ unsigned short sbkt[CHUNK];     // 8 KB bucket id per slot
    int t = threadIdx.x, blk = blockIdx.x;
    for (int i = t; i < MAXNB; i += 256) h[i] = 0;
    __syncthreads();
    int base = blk * CHUNK;
    int4v d4[4], s4[4];
#pragma unroll
    for (int it = 0; it < 4; ++it) {
        int e = base + (it * 256 + t) * 4;
        if (e < E) {                           // E % 4 == 0 -> whole quad valid
            d4[it] = __builtin_nontemporal_load((const int4v*)(dst + e));
            s4[it] = __builtin_nontemporal_load((const int4v*)(src + e));
        } else {
            int sent = NB << LB;               // sentinel bucket NB (skipped at write-out)
            d4[it].x = sent; d4[it].y = sent; d4[it].z = sent; d4[it].w = sent;
            s4[it].x = 0;    s4[it].y = 0;    s4[it].z = 0;    s4[it].w = 0;
        }
        atomicAdd(&h[d4[it].x >> LB], 1);
        atomicAdd(&h[d4[it].y >> LB], 1);
        atomicAdd(&h[d4[it].z >> LB], 1);
        atomicAdd(&h[d4[it].w >> LB], 1);
    }
    __syncthreads();
    for (int i = t; i < MAXNB; i += 256) s[i] = h[i];
    __syncthreads();
    // inclusive Hillis-Steele scan of s[0..1023], 256 threads x 4
    for (int off = 1; off < MAXNB; off <<= 1) {
        int v[4];
#pragma unroll
        for (int j = 0; j < 4; ++j) {
            int i = t + j * 256;
            v[j] = s[i] + ((i >= off) ? s[i - off] : 0);
        }
        __syncthreads();
#pragma unroll
        for (int j = 0; j < 4; ++j) s[t + j * 256] = v[j];
        __syncthreads();
    }
    // h := exclusive prefix (rank cursor); s := dbase = global_start - local_excl
    const int* row = bh + (size_t)blk * NBA;
    for (int i = t; i < MAXNB; i += 256) {
        int excl = s[i] - h[i];
        h[i] = excl;
        s[i] = (i < NB) ? (bucket_base[i] + row[i] - excl) : 0;
    }
    __syncthreads();
    // rank & reorder into LDS
#pragma unroll
    for (int it = 0; it < 4; ++it) {
        int d, sv, b, p;
        d = d4[it].x; sv = s4[it].x; b = d >> LB; p = atomicAdd(&h[b], 1);
        sedge[p] = (sv << 8) | (d & (BUCKET - 1)); sbkt[p] = (unsigned short)b;
        d = d4[it].y; sv = s4[it].y; b = d >> LB; p = atomicAdd(&h[b], 1);
        sedge[p] = (sv << 8) | (d & (BUCKET - 1)); sbkt[p] = (unsigned short)b;
        d = d4[it].z; sv = s4[it].z; b = d >> LB; p = atomicAdd(&h[b], 1);
        sedge[p] = (sv << 8) | (d & (BUCKET - 1)); sbkt[p] = (unsigned short)b;
        d = d4[it].w; sv = s4[it].w; b = d >> LB; p = atomicAdd(&h[b], 1);
        sedge[p] = (sv << 8) | (d & (BUCKET - 1)); sbkt[p] = (unsigned short)b;
    }
    __syncthreads();
    // write-out: consecutive j in a bucket run -> consecutive dest (coalesced bursts)
    for (int j = t; j < CHUNK; j += 256) {
        int b = sbkt[j];
        if (b < NB)
            __builtin_nontemporal_store(sedge[j], bedges + s[b] + j);
    }
}

// ---- per-bucket degree hist -> dinv only ----
__global__ void k_pcount2(const int* __restrict__ bucket_base, const int* __restrict__ bucket_cnt,
                          const int* __restrict__ bedges, float* __restrict__ dinv, int n) {
    __shared__ int cnt[TRASH + 8];             // bins 0..128 (128 = sentinel trash)
    int b = blockIdx.x, t = threadIdx.x;       // 256 threads
    for (int i = t; i < TRASH + 8; i += 256) cnt[i] = 0;
    __syncthreads();
    int base = bucket_base[b], ne = bucket_cnt[b];
    int nqq = (ne + 3) >> 2;
    for (int qi = t; qi < nqq; qi += 256) {
        int4v q = __builtin_nontemporal_load((const int4v*)(bedges + base + (qi << 2)));
        atomicAdd(&cnt[q.x & 255], 1);
        atomicAdd(&cnt[q.y & 255], 1);
        atomicAdd(&cnt[q.z & 255], 1);
        atomicAdd(&cnt[q.w & 255], 1);
    }
    __syncthreads();
    if (t < BUCKET) {
        int node = b * BUCKET + t;
        if (node < n) dinv[node] = rsqrtf((float)(cnt[t] + 1));   // +1 self-loop
    }
}

// -------- GEMM1: K-split x2, LDS-coalesced x staging, pk_fma accumulation --------
__global__ __launch_bounds__(256) void k_gemm1p(
        const float* __restrict__ x, const float* __restrict__ W,
        float* __restrict__ part, int n) {
    __shared__ float xs[RPB * LSTRIDE];        // 33792 B
    int b  = blockIdx.x >> 1;
    int ks = blockIdx.x & 1;
    int r0 = b * RPB;
    int t  = threadIdx.x;
    int r  = r0 + t;
    int kbase = ks * KHALF;

    float2v acc2[F_HID / 2];                   // float2 lanes -> v_pk_fma_f32
#pragma unroll
    for (int c = 0; c < F_HID / 2; ++c) acc2[c] = (float2v){0.0f, 0.0f};

    int lr0 = t >> 3;                           // 0..31 (stage row group)
    int c4  = t & 7;                            // 0..7  (float4 slot: 8 x 16B = 128B/row)

    for (int kc = 0; kc < KHALF; kc += KC) {
        __syncthreads();                        // xs reads of previous chunk done
#pragma unroll
        for (int j = 0; j < 8; ++j) {
            int lr = j * 32 + lr0;
            int gr = r0 + lr;
            float4v v = {0.0f, 0.0f, 0.0f, 0.0f};
            if (gr < n)
                v = *(const float4v*)(x + (size_t)gr * F_IN + kbase + kc + c4 * 4);
            float* d = xs + lr * LSTRIDE + c4 * 4;
            d[0] = v.x; d[1] = v.y; d[2] = v.z; d[3] = v.w;
        }
        __syncthreads();
        if (r < n) {
            const float* xrow = xs + t * LSTRIDE;
            const float2v* Wk2 = (const float2v*)(W + (size_t)(kbase + kc) * F_HID);
#pragma unroll
            for (int k = 0; k < KC; ++k) {
                float xv = xrow[k];
#pragma unroll
                for (int c2 = 0; c2 < F_HID / 2; ++c2)
                    acc2[c2] += xv * Wk2[k * (F_HID / 2) + c2];
            }
        }
    }
    if (r < n) {
        const float* a = (const float*)acc2;
        float4v* o = (float4v*)(part + ((size_t)ks * n + r) * F_HID);
        float4v w0 = {a[0],  a[1],  a[2],  a[3]};
        float4v w1 = {a[4],  a[5],  a[6],  a[7]};
        float4v w2 = {a[8],  a[9],  a[10], a[11]};
        float4v w3 = {a[12], a[13], a[14], a[15]};
        o[0] = w0; o[1] = w1; o[2] = w2; o[3] = w3;
    }
}

// -------- finalize GEMM1: sum K-split partials, scale by dinv, -> bf16 h1b --------
__global__ void k_fin1(const float* __restrict__ part, const float* __restrict__ dinv,
                       unsigned short* __restrict__ h1b, int n) {
    int tg = blockIdx.x * 256 + threadIdx.x;
    int r = tg >> 4, c = tg & 15;
    if (r > n) return;
    if (r == n) { h1b[(size_t)r * F_HID + c] = 0; return; }
    float v = part[(size_t)r * F_HID + c] + part[((size_t)n + r) * F_HID + c];
    h1b[(size_t)r * F_HID + c] = f2bf(dinv[r] * v);
}

// ---- agg layer 1 + relu/bias + GEMM2 fused: 1024 thr, LDS edge staging, quad ILP ----
// 64 groups x 16 lanes; each group processes 4 edges/iter: 4 independent h1b gathers
// hoisted before the conditional ds_add_f32 adds. Edge tile staged coalesced in LDS.
__global__ __launch_bounds__(1024) void k_aggL1(
        const int* __restrict__ bucket_base, const int* __restrict__ bucket_cnt,
        const int* __restrict__ bedges, const unsigned short* __restrict__ h1b,
        const float* __restrict__ dinv, const float* __restrict__ b1,
        const float* __restrict__ W2, unsigned short* __restrict__ h2b, int n) {
    __shared__ float acc[BUCKET * F_HID];      // 8 KB
    __shared__ int se[ATILE];                  // 16 KB staged edges
    int b = blockIdx.x, t = threadIdx.x;
    for (int i = t; i < BUCKET * F_HID; i += 1024) acc[i] = 0.0f;
    int base = bucket_base[b];
    int ne4 = (bucket_cnt[b] + 3) & ~3;        // padded count (pad entries: src=0, dl=TRASH)
    int g = t >> 4, c = t & 15;                // 64 groups x 16 lanes
    for (int tb = 0; tb < ne4; tb += ATILE) {
        int m = min(ATILE, ne4 - tb);
        __syncthreads();                       // prev sweep's se reads done (also covers init)
        int idx = t << 2;
        if (idx < m)
            *(int4v*)(se + idx) = __builtin_nontemporal_load((const int4v*)(bedges + base + tb + idx));
        __syncthreads();
        for (int e0 = (g << 2); e0 < m; e0 += 256) {
            int4v q = *(const int4v*)(se + e0);           // broadcast within group
            float x0 = bf2f(h1b[((size_t)(unsigned)(q.x >> 8) << 4) + c]);
            float x1 = bf2f(h1b[((size_t)(unsigned)(q.y >> 8) << 4) + c]);
            float x2 = bf2f(h1b[((size_t)(unsigned)(q.z >> 8) << 4) + c]);
            float x3 = bf2f(h1b[((size_t)(unsigned)(q.w >> 8) << 4) + c]);
            int d0 = q.x & 255, d1 = q.y & 255, d2 = q.z & 255, d3 = q.w & 255;
            if (d0 < BUCKET) unsafeAtomicAdd(&acc[(d0 << 4) + c], x0);
            if (d1 < BUCKET) unsafeAtomicAdd(&acc[(d1 << 4) + c], x1);
            if (d2 < BUCKET) unsafeAtomicAdd(&acc[(d2 << 4) + c], x2);
            if (d3 < BUCKET) unsafeAtomicAdd(&acc[(d3 << 4) + c], x3);
        }
    }
    __syncthreads();
    // epilogue: self-loop + dinv + relu+b1 + 16x7 GEMM via 16-lane butterfly -> h2b
    for (int nd = g; nd < BUCKET; nd += 64) {
        int node = b * BUCKET + nd;
        if (node < n) {
            float dv = dinv[node];
            float a = acc[(nd << 4) + c] + bf2f(h1b[((size_t)node << 4) + c]);
            float z = fmaxf(dv * a + b1[c], 0.0f);
            float h[F_OUT];
#pragma unroll
            for (int o = 0; o < F_OUT; ++o) h[o] = z * W2[c * F_OUT + o];
#pragma unroll
            for (int sft = 8; sft >= 1; sft >>= 1)
#pragma unroll
                for (int o = 0; o < F_OUT; ++o) h[o] += __shfl_xor(h[o], sft, 16);
            if (c < 8) {
                unsigned short w = (c < F_OUT) ? f2bf(dv * h[c]) : (unsigned short)0;
                h2b[((size_t)node << 3) + c] = w;
            }
        }
    }
}

// ---- agg layer 2 + bias fused: 1024 thr, LDS edge staging, quad ILP -> out ----
__global__ __launch_bounds__(1024) void k_aggL2(
        const int* __restrict__ bucket_base, const int* __restrict__ bucket_cnt,
        const int* __restrict__ bedges, const unsigned short* __restrict__ h2b,
        const float* __restrict__ dinv, const float* __restrict__ b2,
        float* __restrict__ out, int n) {
    __shared__ float acc[BUCKET * 8];          // 4 KB
    __shared__ int se[ATILE];                  // 16 KB staged edges
    int b = blockIdx.x, t = threadIdx.x;
    for (int i = t; i < BUCKET * 8; i += 1024) acc[i] = 0.0f;
    int base = bucket_base[b];
    int ne4 = (bucket_cnt[b] + 3) & ~3;
    int g = t >> 3, c = t & 7;                 // 128 groups x 8 lanes
    for (int tb = 0; tb < ne4; tb += ATILE) {
        int m = min(ATILE, ne4 - tb);
        __syncthreads();
        int idx = t << 2;
        if (idx < m)
            *(int4v*)(se + idx) = __builtin_nontemporal_load((const int4v*)(bedges + base + tb + idx));
        __syncthreads();
        for (int e0 = (g << 2); e0 < m; e0 += 512) {
            int4v q = *(const int4v*)(se + e0);
            float x0 = bf2f(h2b[((size_t)(unsigned)(q.x >> 8) << 3) + c]);
            float x1 = bf2f(h2b[((size_t)(unsigned)(q.y >> 8) << 3) + c]);
            float x2 = bf2f(h2b[((size_t)(unsigned)(q.z >> 8) << 3) + c]);
            float x3 = bf2f(h2b[((size_t)(unsigned)(q.w >> 8) << 3) + c]);
            int d0 = q.x & 255, d1 = q.y & 255, d2 = q.z & 255, d3 = q.w & 255;
            if (d0 < BUCKET) unsafeAtomicAdd(&acc[(d0 << 3) + c], x0);
            if (d1 < BUCKET) unsafeAtomicAdd(&acc[(d1 << 3) + c], x1);
            if (d2 < BUCKET) unsafeAtomicAdd(&acc[(d2 << 3) + c], x2);
            if (d3 < BUCKET) unsafeAtomicAdd(&acc[(d3 << 3) + c], x3);
        }
    }
    __syncthreads();
    for (int nd = g; nd < BUCKET; nd += 128) {
        int node = b * BUCKET + nd;
        if (node < n && c < F_OUT) {
            float a = acc[(nd << 3) + c] + bf2f(h2b[((size_t)node << 3) + c]);
            out[(size_t)node * F_OUT + c] = dinv[node] * a + b2[c];
        }
    }
}

extern "C" void kernel_launch(void* const* d_in, const int* in_sizes, int n_in,
                              void* d_out, int out_size, void* d_ws, size_t ws_size,
                              hipStream_t stream) {
    const float* x  = (const float*)d_in[0];
    const int*   ei = (const int*)d_in[1];      // int64 in source but JAX x64 off -> int32
    const float* W1 = (const float*)d_in[2];
    const float* b1 = (const float*)d_in[3];
    const float* W2 = (const float*)d_in[4];
    const float* b2 = (const float*)d_in[5];
    float* out = (float*)d_out;

    const int n = in_sizes[0] / F_IN;       // 100000
    const int E = in_sizes[1] / 2;          // 3200000
    const int* src = ei;
    const int* dst = ei + E;

    const int NB = (n + BUCKET - 1) / BUCKET;   // 782 (<= MAXNB-1: sentinel bucket NB fits)
    const int NBA = (NB + 3) & ~3;              // 784 (16B-aligned rows)
    const int PBLK = (E + CHUNK - 1) / CHUNK;   // 782

    // workspace layout (16B-aligned sections)
    size_t Np = ((size_t)n + 3) & ~(size_t)3;
    char* ws = (char*)d_ws;
    int*   bucket_cnt   = (int*)ws;             ws += MAXNB * 4;
    int*   bucket_base  = (int*)ws;             ws += MAXNB * 4;
    int*   bh           = (int*)ws;             ws += (size_t)PBLK * NBA * 4;   // 2.45 MB
    float* dinv         = (float*)ws;           ws += Np * 4;
    int*   bedges       = (int*)ws;             ws += ((size_t)E + 4 * MAXNB) * 4;  // 12.8 MB, live to end
    float* part         = (float*)ws;           ws += (size_t)2 * Np * F_HID * 4;   // 12.8 MB
    unsigned short* h1b = (unsigned short*)ws;  ws += (Np + 4) * F_HID * 2;         // 3.2 MB
    unsigned short* h2b = (unsigned short*)ws;  ws += (Np + 4) * 8 * 2;             // 1.6 MB

    k_hist   <<<PBLK, 256, 0, stream>>>(dst, bh, E, NB, NBA);
    k_cscan  <<<NB, 64, 0, stream>>>(bh, bucket_cnt, PBLK, NBA);
    k_bscan1 <<<1, 1024, 0, stream>>>(bucket_cnt, bucket_base, bedges, NB);
    k_place3 <<<PBLK, 256, 0, stream>>>(src, dst, bucket_base, bh, bedges, E, NB, NBA);
    k_pcount2<<<NB, 256, 0, stream>>>(bucket_base, bucket_cnt, bedges, dinv, n);
    k_gemm1p <<<((n + RPB - 1) / RPB) * 2, 256, 0, stream>>>(x, W1, part, n);
    k_fin1   <<<((n + 1) * 16 + 255) / 256, 256, 0, stream>>>(part, dinv, h1b, n);
    k_aggL1  <<<NB, 1024, 0, stream>>>(bucket_base, bucket_cnt, bedges, h1b, dinv, b1, W2, h2b, n);
    k_aggL2  <<<NB, 1024, 0, stream>>>(bucket_base, bucket_cnt, bedges, h2b, dinv, b2, out, n);
}

// Round 6
// 483.577 us; speedup vs baseline: 1.8940x; 1.8932x over previous
//
#include <hip/hip_runtime.h>

#define F_IN 512
#define F_HID 16
#define F_OUT 7
#define BUCKET 128          // nodes per bucket
#define LB 7                // log2(BUCKET)
#define TRASH 128           // dl value for sentinel pad edges in bedges
#define PADV 128            // packed sentinel: src=0, dl=TRASH
#define CHUNK 4096          // edges per partition block
#define MAXNB 1024          // max buckets supported by scans

// GEMM1 tiling
#define RPB 256             // rows per block
#define KC 32               // staged k-chunk
#define KHALF 256           // K range per split block (F_IN / KSPLIT)
#define LSTRIDE 33          // LDS row stride (pad: 2-way bank aliasing = free)

typedef int   int4v   __attribute__((ext_vector_type(4)));
typedef float float2v __attribute__((ext_vector_type(2)));
typedef float float4v __attribute__((ext_vector_type(4)));
typedef unsigned int uint4v __attribute__((ext_vector_type(4)));

static __device__ __forceinline__ unsigned short f2bf(float f) {   // RNE
    unsigned int u = __float_as_uint(f);
    u += 0x7FFFu + ((u >> 16) & 1u);
    return (unsigned short)(u >> 16);
}
static __device__ __forceinline__ float bf2f(unsigned short s) {
    return __uint_as_float((unsigned int)s << 16);
}

// ---------------- hist: per-block LDS histogram -> coalesced global row ----------------
__global__ __launch_bounds__(256) void k_hist(const int* __restrict__ dst,
                                              int* __restrict__ bh, int E, int NB, int NBA) {
    __shared__ int hist[MAXNB];
    int t = threadIdx.x, blk = blockIdx.x;
    for (int i = t; i < NB; i += 256) hist[i] = 0;
    __syncthreads();
    int base = blk * CHUNK;
#pragma unroll
    for (int it = 0; it < CHUNK / 1024; ++it) {
        int e = base + (it * 256 + t) * 4;
        if (e < E) {                                   // E % 4 == 0 -> whole quad valid
            int4v d4 = __builtin_nontemporal_load((const int4v*)(dst + e));
            atomicAdd(&hist[d4.x >> LB], 1);
            atomicAdd(&hist[d4.y >> LB], 1);
            atomicAdd(&hist[d4.z >> LB], 1);
            atomicAdd(&hist[d4.w >> LB], 1);
        }
    }
    __syncthreads();
    int* row = bh + (size_t)blk * NBA;
    for (int i = t; i < NB; i += 256) row[i] = hist[i];
}

// ---------------- column scan: bh column i -> exclusive prefix over blocks ----------------
__global__ __launch_bounds__(64) void k_cscan(int* __restrict__ bh, int* __restrict__ bucket_cnt,
                                              int PBLK, int NBA) {
    int i = blockIdx.x;            // bucket
    int lane = threadIdx.x;        // 0..63
    int carry = 0;
    for (int k0 = 0; k0 < PBLK; k0 += 64) {
        int b = k0 + lane;
        int v = (b < PBLK) ? bh[(size_t)b * NBA + i] : 0;
        int s = v;
#pragma unroll
        for (int off = 1; off < 64; off <<= 1) {
            int u = __shfl_up(s, off);
            if (lane >= off) s += u;
        }
        if (b < PBLK) bh[(size_t)b * NBA + i] = carry + s - v;   // exclusive prefix
        carry += __shfl(s, 63);
    }
    if (lane == 0) bucket_cnt[i] = carry;
}

// ---- scan 1: exclusive scan of 4-aligned bucket counts + sentinel pad tails ----
__global__ void k_bscan1(const int* __restrict__ bucket_cnt, int* __restrict__ bucket_base,
                         int* __restrict__ bedges, int NB) {
    __shared__ int sm[MAXNB];
    int t = threadIdx.x;                       // 1024 threads
    int c = (t < NB) ? bucket_cnt[t] : 0;
    int ca = (c + 3) & ~3;
    sm[t] = ca;
    __syncthreads();
    for (int off = 1; off < MAXNB; off <<= 1) {
        int v = sm[t];
        int add = (t >= off) ? sm[t - off] : 0;
        __syncthreads();
        sm[t] = v + add;
        __syncthreads();
    }
    if (t < NB) {
        int base = sm[t] - ca;
        bucket_base[t] = base;
        for (int i = c; i < ca; ++i) bedges[base + i] = PADV;
    }
}

// ------- place: block rank-and-reorder, then run-coalesced write-out (low write-amp) -------
__global__ __launch_bounds__(256) void k_place3(
        const int* __restrict__ src, const int* __restrict__ dst,
        const int* __restrict__ bucket_base, const int* __restrict__ bh,
        int* __restrict__ bedges, int E, int NB, int NBA) {
    __shared__ int h[MAXNB];                   // hist -> exclusive cursor
    __shared__ int s[MAXNB];                   // inclusive scan -> dbase
    __shared__ int sedge[CHUNK];               // 16 KB reordered packed edges
    __shared__ unsigned short sbkt[CHUNK];     // 8 KB bucket id per slot
    int t = threadIdx.x, blk = blockIdx.x;
    for (int i = t; i < MAXNB; i += 256) h[i] = 0;
    __syncthreads();
    int base = blk * CHUNK;
    int4v d4[4], s4[4];
#pragma unroll
    for (int it = 0; it < 4; ++it) {
        int e = base + (it * 256 + t) * 4;
        if (e < E) {                           // E % 4 == 0 -> whole quad valid
            d4[it] = __builtin_nontemporal_load((const int4v*)(dst + e));
            s4[it] = __builtin_nontemporal_load((const int4v*)(src + e));
        } else {
            int sent = NB << LB;               // sentinel bucket NB (skipped at write-out)
            d4[it].x = sent; d4[it].y = sent; d4[it].z = sent; d4[it].w = sent;
            s4[it].x = 0;    s4[it].y = 0;    s4[it].z = 0;    s4[it].w = 0;
        }
        atomicAdd(&h[d4[it].x >> LB], 1);
        atomicAdd(&h[d4[it].y >> LB], 1);
        atomicAdd(&h[d4[it].z >> LB], 1);
        atomicAdd(&h[d4[it].w >> LB], 1);
    }
    __syncthreads();
    for (int i = t; i < MAXNB; i += 256) s[i] = h[i];
    __syncthreads();
    // inclusive Hillis-Steele scan of s[0..1023], 256 threads x 4
    for (int off = 1; off < MAXNB; off <<= 1) {
        int v[4];
#pragma unroll
        for (int j = 0; j < 4; ++j) {
            int i = t + j * 256;
            v[j] = s[i] + ((i >= off) ? s[i - off] : 0);
        }
        __syncthreads();
#pragma unroll
        for (int j = 0; j < 4; ++j) s[t + j * 256] = v[j];
        __syncthreads();
    }
    // h := exclusive prefix (rank cursor); s := dbase = global_start - local_excl
    const int* row = bh + (size_t)blk * NBA;
    for (int i = t; i < MAXNB; i += 256) {
        int excl = s[i] - h[i];
        h[i] = excl;
        s[i] = (i < NB) ? (bucket_base[i] + row[i] - excl) : 0;
    }
    __syncthreads();
    // rank & reorder into LDS
#pragma unroll
    for (int it = 0; it < 4; ++it) {
        int d, sv, b, p;
        d = d4[it].x; sv = s4[it].x; b = d >> LB; p = atomicAdd(&h[b], 1);
        sedge[p] = (sv << 8) | (d & (BUCKET - 1)); sbkt[p] = (unsigned short)b;
        d = d4[it].y; sv = s4[it].y; b = d >> LB; p = atomicAdd(&h[b], 1);
        sedge[p] = (sv << 8) | (d & (BUCKET - 1)); sbkt[p] = (unsigned short)b;
        d = d4[it].z; sv = s4[it].z; b = d >> LB; p = atomicAdd(&h[b], 1);
        sedge[p] = (sv << 8) | (d & (BUCKET - 1)); sbkt[p] = (unsigned short)b;
        d = d4[it].w; sv = s4[it].w; b = d >> LB; p = atomicAdd(&h[b], 1);
        sedge[p] = (sv << 8) | (d & (BUCKET - 1)); sbkt[p] = (unsigned short)b;
    }
    __syncthreads();
    // write-out: consecutive j in a bucket run -> consecutive dest (coalesced bursts)
    for (int j = t; j < CHUNK; j += 256) {
        int b = sbkt[j];
        if (b < NB)
            __builtin_nontemporal_store(sedge[j], bedges + s[b] + j);
    }
}

// ---- per-bucket: degree hist -> dinv, within-bucket 4-padded offsets, bucket padded size ----
__global__ void k_pcount(const int* __restrict__ bucket_base, const int* __restrict__ bucket_cnt,
                         const int* __restrict__ bedges, float* __restrict__ dinv,
                         int* __restrict__ node_off, int* __restrict__ bucket_psize, int n) {
    __shared__ int cnt[TRASH + 8];             // bins 0..128 (128 = sentinel trash)
    __shared__ int sc[BUCKET];
    int b = blockIdx.x, t = threadIdx.x;       // 256 threads
    for (int i = t; i < TRASH + 8; i += 256) cnt[i] = 0;
    __syncthreads();
    int base = bucket_base[b], ne = bucket_cnt[b];
    int nqq = (ne + 3) >> 2;
    for (int qi = t; qi < nqq; qi += 256) {
        int4v q = __builtin_nontemporal_load((const int4v*)(bedges + base + (qi << 2)));
        atomicAdd(&cnt[q.x & 255], 1);
        atomicAdd(&cnt[q.y & 255], 1);
        atomicAdd(&cnt[q.z & 255], 1);
        atomicAdd(&cnt[q.w & 255], 1);
    }
    __syncthreads();
    int p = 0;
    if (t < BUCKET) { p = (cnt[t] + 3) & ~3; sc[t] = p; }
    __syncthreads();
    for (int off = 1; off < BUCKET; off <<= 1) {
        int v = 0;
        if (t < BUCKET) { v = sc[t]; if (t >= off) v += sc[t - off]; }
        __syncthreads();
        if (t < BUCKET) sc[t] = v;
        __syncthreads();
    }
    if (t < BUCKET) {
        int node = b * BUCKET + t;
        if (node < n) {
            dinv[node] = rsqrtf((float)(cnt[t] + 1));   // +1 self-loop
            node_off[node] = sc[t] - p;                 // within-bucket padded offset (woff)
        }
        if (t == BUCKET - 1) bucket_psize[b] = sc[t];
    }
}

// ---- scan 2: exclusive scan of padded bucket sizes -> pbase ----
__global__ void k_bscan2(const int* __restrict__ bucket_psize, int* __restrict__ pbase, int NB) {
    __shared__ int sm[MAXNB];
    int t = threadIdx.x;                       // 1024 threads
    int c = (t < NB) ? bucket_psize[t] : 0;
    sm[t] = c;
    __syncthreads();
    for (int off = 1; off < MAXNB; off <<= 1) {
        int v = sm[t];
        int add = (t >= off) ? sm[t - off] : 0;
        __syncthreads();
        sm[t] = v + add;
        __syncthreads();
    }
    if (t < NB) pbase[t] = sm[t] - c;
}

// ---- per-bucket counting sort by dl: bedges -> bedges2 (src only, per-node 4-padded runs) ----
__global__ void k_sort(const int* __restrict__ bucket_base, const int* __restrict__ bucket_cnt,
                       const int* __restrict__ pbase, const int* __restrict__ bedges,
                       int* __restrict__ bedges2, int* __restrict__ node_off,
                       int* __restrict__ node_nq, int n) {
    __shared__ int cur[BUCKET];
    __shared__ int woffs[BUCKET];
    int b = blockIdx.x, t = threadIdx.x;       // 256 threads
    int pb = pbase[b];
    if (t < BUCKET) {
        int node = b * BUCKET + t;
        int w = (node < n) ? node_off[node] : 0;
        woffs[t] = w;
        cur[t] = w;
    }
    __syncthreads();
    int base = bucket_base[b], ne = bucket_cnt[b];
    int nqq = (ne + 3) >> 2;
    for (int qi = t; qi < nqq; qi += 256) {
        int4v q = __builtin_nontemporal_load((const int4v*)(bedges + base + (qi << 2)));
        int v, dl, pos;
        v = q.x; dl = v & 255;
        if (dl < BUCKET) { pos = atomicAdd(&cur[dl], 1); bedges2[pb + pos] = v >> 8; }
        v = q.y; dl = v & 255;
        if (dl < BUCKET) { pos = atomicAdd(&cur[dl], 1); bedges2[pb + pos] = v >> 8; }
        v = q.z; dl = v & 255;
        if (dl < BUCKET) { pos = atomicAdd(&cur[dl], 1); bedges2[pb + pos] = v >> 8; }
        v = q.w; dl = v & 255;
        if (dl < BUCKET) { pos = atomicAdd(&cur[dl], 1); bedges2[pb + pos] = v >> 8; }
    }
    __syncthreads();
    if (t < BUCKET) {
        int node = b * BUCKET + t;
        if (node < n) {
            int w = woffs[t];
            int endc = cur[t];
            int cnt = endc - w;
            int p = (cnt + 3) & ~3;
            for (int i = endc; i < w + p; ++i) bedges2[pb + i] = n;   // sentinel -> zero row
            node_off[node] = pb + w;                                  // now GLOBAL offset
            node_nq[node] = p >> 2;
        }
    }
}

// -------- GEMM1: K-split x2, LDS-coalesced x staging, pk_fma accumulation --------
__global__ __launch_bounds__(256) void k_gemm1p(
        const float* __restrict__ x, const float* __restrict__ W,
        float* __restrict__ part, int n) {
    __shared__ float xs[RPB * LSTRIDE];        // 33792 B
    int b  = blockIdx.x >> 1;
    int ks = blockIdx.x & 1;
    int r0 = b * RPB;
    int t  = threadIdx.x;
    int r  = r0 + t;
    int kbase = ks * KHALF;

    float2v acc2[F_HID / 2];                   // float2 lanes -> v_pk_fma_f32
#pragma unroll
    for (int c = 0; c < F_HID / 2; ++c) acc2[c] = (float2v){0.0f, 0.0f};

    int lr0 = t >> 3;                           // 0..31 (stage row group)
    int c4  = t & 7;                            // 0..7  (float4 slot: 8 x 16B = 128B/row)

    for (int kc = 0; kc < KHALF; kc += KC) {
        __syncthreads();                        // xs reads of previous chunk done
#pragma unroll
        for (int j = 0; j < 8; ++j) {
            int lr = j * 32 + lr0;
            int gr = r0 + lr;
            float4v v = {0.0f, 0.0f, 0.0f, 0.0f};
            if (gr < n)
                v = *(const float4v*)(x + (size_t)gr * F_IN + kbase + kc + c4 * 4);
            float* d = xs + lr * LSTRIDE + c4 * 4;
            d[0] = v.x; d[1] = v.y; d[2] = v.z; d[3] = v.w;
        }
        __syncthreads();
        if (r < n) {
            const float* xrow = xs + t * LSTRIDE;
            const float2v* Wk2 = (const float2v*)(W + (size_t)(kbase + kc) * F_HID);
#pragma unroll
            for (int k = 0; k < KC; ++k) {
                float xv = xrow[k];
#pragma unroll
                for (int c2 = 0; c2 < F_HID / 2; ++c2)
                    acc2[c2] += xv * Wk2[k * (F_HID / 2) + c2];
            }
        }
    }
    if (r < n) {
        const float* a = (const float*)acc2;
        float4v* o = (float4v*)(part + ((size_t)ks * n + r) * F_HID);
        float4v w0 = {a[0],  a[1],  a[2],  a[3]};
        float4v w1 = {a[4],  a[5],  a[6],  a[7]};
        float4v w2 = {a[8],  a[9],  a[10], a[11]};
        float4v w3 = {a[12], a[13], a[14], a[15]};
        o[0] = w0; o[1] = w1; o[2] = w2; o[3] = w3;
    }
}

// -------- finalize GEMM1: sum K-split partials, scale by dinv, -> bf16 h1b --------
__global__ void k_fin1(const float* __restrict__ part, const float* __restrict__ dinv,
                       unsigned short* __restrict__ h1b, int n) {
    int tg = blockIdx.x * 256 + threadIdx.x;
    int r = tg >> 4, c = tg & 15;
    if (r > n) return;
    if (r == n) { h1b[(size_t)r * F_HID + c] = 0; return; }
    float v = part[(size_t)r * F_HID + c] + part[((size_t)n + r) * F_HID + c];
    h1b[(size_t)r * F_HID + c] = f2bf(dinv[r] * v);
}

// ---- agg layer 1 + relu/bias + GEMM2 fused: 16 lanes/node, CSR quads, REG accumulation ----
// Register accumulation (no LDS atomics: ~0 lane-atomic/edge). Epilogue: dinv scale,
// relu+b1, 16x7 GEMM via 16-lane shfl_xor butterfly, h2b write (stride 8, col7=0).
__global__ __launch_bounds__(1024) void k_aggF1(
        const int* __restrict__ node_off, const int* __restrict__ node_nq,
        const int* __restrict__ bedges2, const unsigned short* __restrict__ h1b,
        const float* __restrict__ dinv, const float* __restrict__ b1,
        const float* __restrict__ W2, unsigned short* __restrict__ h2b, int n) {
    int tg = blockIdx.x * 1024 + threadIdx.x;
    int node = tg >> 4, c = tg & 15;
    if (node >= n) return;
    int off = node_off[node], nq = node_nq[node];
    float acc = bf2f(h1b[(size_t)node * F_HID + c]);    // self-loop (pre-scaled)
    for (int q = 0; q < nq; ++q) {
        int4v s = *(const int4v*)(bedges2 + off + (q << 2));
        float v0 = bf2f(h1b[(size_t)s.x * F_HID + c]);
        float v1 = bf2f(h1b[(size_t)s.y * F_HID + c]);
        float v2 = bf2f(h1b[(size_t)s.z * F_HID + c]);
        float v3 = bf2f(h1b[(size_t)s.w * F_HID + c]);
        acc += v0 + v1 + v2 + v3;
    }
    float dv = dinv[node];
    float z = fmaxf(dv * acc + b1[c], 0.0f);
    float h[F_OUT];
#pragma unroll
    for (int o = 0; o < F_OUT; ++o) h[o] = z * W2[c * F_OUT + o];
#pragma unroll
    for (int sft = 8; sft >= 1; sft >>= 1)
#pragma unroll
        for (int o = 0; o < F_OUT; ++o) h[o] += __shfl_xor(h[o], sft, 16);
    if (c < 8) {
        unsigned short w = (c < F_OUT) ? f2bf(dv * h[c]) : (unsigned short)0;
        h2b[((size_t)node << 3) + c] = w;
    }
}

// ------ agg layer 2 + bias fused: 8 lanes/node, CSR quads, register accumulation ------
__global__ __launch_bounds__(1024) void k_aggF2(
        const int* __restrict__ node_off, const int* __restrict__ node_nq,
        const int* __restrict__ bedges2, const unsigned short* __restrict__ h2b,
        const float* __restrict__ dinv, const float* __restrict__ b2,
        float* __restrict__ out, int n) {
    int tg = blockIdx.x * 1024 + threadIdx.x;
    int node = tg >> 3, c = tg & 7;
    if (node >= n) return;
    int off = node_off[node], nq = node_nq[node];
    float acc = bf2f(h2b[((size_t)node << 3) + c]);     // self-loop (col7 = 0)
    for (int q = 0; q < nq; ++q) {
        int4v s = *(const int4v*)(bedges2 + off + (q << 2));
        float v0 = bf2f(h2b[((size_t)s.x << 3) + c]);
        float v1 = bf2f(h2b[((size_t)s.y << 3) + c]);
        float v2 = bf2f(h2b[((size_t)s.z << 3) + c]);
        float v3 = bf2f(h2b[((size_t)s.w << 3) + c]);
        acc += v0 + v1 + v2 + v3;
    }
    if (c < F_OUT)
        out[(size_t)node * F_OUT + c] = dinv[node] * acc + b2[c];
}

extern "C" void kernel_launch(void* const* d_in, const int* in_sizes, int n_in,
                              void* d_out, int out_size, void* d_ws, size_t ws_size,
                              hipStream_t stream) {
    const float* x  = (const float*)d_in[0];
    const int*   ei = (const int*)d_in[1];      // int64 in source but JAX x64 off -> int32
    const float* W1 = (const float*)d_in[2];
    const float* b1 = (const float*)d_in[3];
    const float* W2 = (const float*)d_in[4];
    const float* b2 = (const float*)d_in[5];
    float* out = (float*)d_out;

    const int n = in_sizes[0] / F_IN;       // 100000
    const int E = in_sizes[1] / 2;          // 3200000
    const int* src = ei;
    const int* dst = ei + E;

    const int NB = (n + BUCKET - 1) / BUCKET;   // 782 (<= MAXNB-1: sentinel bucket NB fits)
    const int NBA = (NB + 3) & ~3;              // 784 (16B-aligned rows)
    const int PBLK = (E + CHUNK - 1) / CHUNK;   // 782

    // workspace layout (16B-aligned sections)
    size_t Np = ((size_t)n + 3) & ~(size_t)3;
    char* ws = (char*)d_ws;
    int*   bucket_cnt   = (int*)ws;             ws += MAXNB * 4;
    int*   bucket_base  = (int*)ws;             ws += MAXNB * 4;
    int*   bucket_psize = (int*)ws;             ws += MAXNB * 4;
    int*   pbase        = (int*)ws;             ws += MAXNB * 4;
    int*   bh           = (int*)ws;             ws += (size_t)PBLK * NBA * 4;   // 2.45 MB
    float* dinv         = (float*)ws;           ws += Np * 4;
    int*   node_off     = (int*)ws;             ws += Np * 4;
    int*   node_nq      = (int*)ws;             ws += Np * 4;
    int*   bedges       = (int*)ws;             ws += ((size_t)E + 4 * MAXNB) * 4;  // 12.82 MB
    int*   bedges2      = (int*)ws;             ws += ((size_t)E + 4 * Np) * 4;     // 14.4 MB
    unsigned short* h1b = (unsigned short*)ws;  ws += (Np + 4) * F_HID * 2;         // 3.2 MB
    unsigned short* h2b = (unsigned short*)ws;  ws += (Np + 4) * 8 * 2;             // 1.6 MB
    // bedges region dead after k_sort; reused as fp32 GEMM1 partials
    // (2*n*16*4 = 12.80 MB <= 12.82 MB), dead after k_fin1.
    float* part         = (float*)bedges;

    k_hist   <<<PBLK, 256, 0, stream>>>(dst, bh, E, NB, NBA);
    k_cscan  <<<NB, 64, 0, stream>>>(bh, bucket_cnt, PBLK, NBA);
    k_bscan1 <<<1, 1024, 0, stream>>>(bucket_cnt, bucket_base, bedges, NB);
    k_place3 <<<PBLK, 256, 0, stream>>>(src, dst, bucket_base, bh, bedges, E, NB, NBA);
    k_pcount <<<NB, 256, 0, stream>>>(bucket_base, bucket_cnt, bedges, dinv, node_off, bucket_psize, n);
    k_bscan2 <<<1, 1024, 0, stream>>>(bucket_psize, pbase, NB);
    k_sort   <<<NB, 256, 0, stream>>>(bucket_base, bucket_cnt, pbase, bedges, bedges2, node_off, node_nq, n);
    k_gemm1p <<<((n + RPB - 1) / RPB) * 2, 256, 0, stream>>>(x, W1, part, n);
    k_fin1   <<<((n + 1) * 16 + 255) / 256, 256, 0, stream>>>(part, dinv, h1b, n);
    k_aggF1  <<<((size_t)n * 16 + 1023) / 1024, 1024, 0, stream>>>(node_off, node_nq, bedges2, h1b, dinv, b1, W2, h2b, n);
    k_aggF2  <<<((size_t)n * 8 + 1023) / 1024, 1024, 0, stream>>>(node_off, node_nq, bedges2, h2b, dinv, b2, out, n);
}

// Round 7
// 461.613 us; speedup vs baseline: 1.9841x; 1.0476x over previous
//
#include <hip/hip_runtime.h>

#define F_IN 512
#define F_HID 16
#define F_OUT 7
#define BUCKET 128          // nodes per bucket
#define LB 7                // log2(BUCKET)
#define CHUNK 4096          // edges per partition block
#define MAXNB 1024          // max buckets supported by block-local scans
#define BSTR 8192           // bedges fixed bucket stride (mean 4092, sigma 64 -> 64-sigma safe)
#define BSTR2 8704          // bedges2 fixed stride (BSTR + 128*4 pad headroom)

// GEMM1 tiling
#define RPB 256             // rows per block
#define KC 32               // staged k-chunk
#define KHALF 256           // K range per split block (F_IN / KSPLIT)
#define LSTRIDE 33          // LDS row stride (pad: 2-way bank aliasing = free)

typedef int   int4v   __attribute__((ext_vector_type(4)));
typedef float float2v __attribute__((ext_vector_type(2)));
typedef float float4v __attribute__((ext_vector_type(4)));
typedef unsigned int uint4v __attribute__((ext_vector_type(4)));

static __device__ __forceinline__ unsigned short f2bf(float f) {   // RNE
    unsigned int u = __float_as_uint(f);
    u += 0x7FFFu + ((u >> 16) & 1u);
    return (unsigned short)(u >> 16);
}
static __device__ __forceinline__ float bf2f(unsigned short s) {
    return __uint_as_float((unsigned int)s << 16);
}

// ---------------- init: fixed-stride bucket cursors ----------------
__global__ void k_init(int* __restrict__ cursor, int NB) {
    int i = blockIdx.x * 256 + threadIdx.x;
    if (i < NB) cursor[i] = i * BSTR;
}

// ------- place: block rank-and-reorder; global dest via per-bucket atomic cursors -------
// No pre-pass histogram/prefix needed: bucket b's region is [b*BSTR, b*BSTR+cnt_b).
__global__ __launch_bounds__(256) void k_place4(
        const int* __restrict__ src, const int* __restrict__ dst,
        int* __restrict__ cursor, int* __restrict__ bedges, int E, int NB) {
    __shared__ int h[MAXNB];                   // hist -> exclusive rank cursor
    __shared__ int s[MAXNB];                   // inclusive scan -> dbase
    __shared__ int sedge[CHUNK];               // 16 KB reordered packed edges
    __shared__ unsigned short sbkt[CHUNK];     // 8 KB bucket id per slot
    int t = threadIdx.x, blk = blockIdx.x;
    for (int i = t; i < MAXNB; i += 256) h[i] = 0;
    __syncthreads();
    int base = blk * CHUNK;
    int4v d4[4], s4[4];
#pragma unroll
    for (int it = 0; it < 4; ++it) {
        int e = base + (it * 256 + t) * 4;
        if (e < E) {                           // E % 4 == 0 -> whole quad valid
            d4[it] = __builtin_nontemporal_load((const int4v*)(dst + e));
            s4[it] = __builtin_nontemporal_load((const int4v*)(src + e));
        } else {
            int sent = NB << LB;               // sentinel bucket NB (skipped at write-out)
            d4[it].x = sent; d4[it].y = sent; d4[it].z = sent; d4[it].w = sent;
            s4[it].x = 0;    s4[it].y = 0;    s4[it].z = 0;    s4[it].w = 0;
        }
        atomicAdd(&h[d4[it].x >> LB], 1);
        atomicAdd(&h[d4[it].y >> LB], 1);
        atomicAdd(&h[d4[it].z >> LB], 1);
        atomicAdd(&h[d4[it].w >> LB], 1);
    }
    __syncthreads();
    for (int i = t; i < MAXNB; i += 256) s[i] = h[i];
    __syncthreads();
    // inclusive Hillis-Steele scan of s[0..1023], 256 threads x 4
    for (int off = 1; off < MAXNB; off <<= 1) {
        int v[4];
#pragma unroll
        for (int j = 0; j < 4; ++j) {
            int i = t + j * 256;
            v[j] = s[i] + ((i >= off) ? s[i - off] : 0);
        }
        __syncthreads();
#pragma unroll
        for (int j = 0; j < 4; ++j) s[t + j * 256] = v[j];
        __syncthreads();
    }
    // h := exclusive rank base; s := dbase = (atomic run reservation) - local_excl
    for (int i = t; i < MAXNB; i += 256) {
        int incl = s[i], cnt = h[i];
        int excl = incl - cnt;
        h[i] = excl;
        int db = 0;
        if (i < NB && cnt > 0)
            db = atomicAdd(&cursor[i], cnt) - excl;    // device-scope global atomic
        s[i] = db;
    }
    __syncthreads();
    // rank & reorder into LDS
#pragma unroll
    for (int it = 0; it < 4; ++it) {
        int d, sv, b, p;
        d = d4[it].x; sv = s4[it].x; b = d >> LB; p = atomicAdd(&h[b], 1);
        sedge[p] = (sv << 8) | (d & (BUCKET - 1)); sbkt[p] = (unsigned short)b;
        d = d4[it].y; sv = s4[it].y; b = d >> LB; p = atomicAdd(&h[b], 1);
        sedge[p] = (sv << 8) | (d & (BUCKET - 1)); sbkt[p] = (unsigned short)b;
        d = d4[it].z; sv = s4[it].z; b = d >> LB; p = atomicAdd(&h[b], 1);
        sedge[p] = (sv << 8) | (d & (BUCKET - 1)); sbkt[p] = (unsigned short)b;
        d = d4[it].w; sv = s4[it].w; b = d >> LB; p = atomicAdd(&h[b], 1);
        sedge[p] = (sv << 8) | (d & (BUCKET - 1)); sbkt[p] = (unsigned short)b;
    }
    __syncthreads();
    // write-out: consecutive j in a bucket run -> consecutive dest (coalesced bursts)
    for (int j = t; j < CHUNK; j += 256) {
        int b = sbkt[j];
        if (b < NB)
            __builtin_nontemporal_store(sedge[j], bedges + s[b] + j);
    }
}

// ---- psort: fused degree-count + scan + counting-sort; coalesced bedges2 write-out ----
// One block per bucket. Pass 1: count per-node degree (quads, L2->LDS atomics).
// Scan padded counts -> dinv / node_off / node_nq. Pass 2: rank edges into LDS
// (bucket is L2-hot from pass 1), sentinel-pad, then linear quad write to bedges2.
__global__ __launch_bounds__(256) void k_psort(
        const int* __restrict__ cursor, const int* __restrict__ bedges,
        int* __restrict__ bedges2, float* __restrict__ dinv,
        int* __restrict__ node_off, int* __restrict__ node_nq, int n) {
    __shared__ int cnt[BUCKET];
    __shared__ int sc[BUCKET];                 // padded inclusive scan
    __shared__ int cur[BUCKET];
    __shared__ int sedge[BSTR2];               // 34 KB ranked srcs
    int b = blockIdx.x, t = threadIdx.x;
    int base = b * BSTR;
    int ne = cursor[b] - base;
    if (t < BUCKET) cnt[t] = 0;
    __syncthreads();
    int nq = ne >> 2, tail = ne & 3;
    for (int q = t; q < nq; q += 256) {
        int4v v = *(const int4v*)(bedges + base + (q << 2));
        atomicAdd(&cnt[v.x & 127], 1);
        atomicAdd(&cnt[v.y & 127], 1);
        atomicAdd(&cnt[v.z & 127], 1);
        atomicAdd(&cnt[v.w & 127], 1);
    }
    if (t < tail) atomicAdd(&cnt[bedges[base + (nq << 2) + t] & 127], 1);
    __syncthreads();
    int p = 0;
    if (t < BUCKET) { p = (cnt[t] + 3) & ~3; sc[t] = p; }
    __syncthreads();
    for (int off = 1; off < BUCKET; off <<= 1) {
        int v = 0;
        if (t < BUCKET) { v = sc[t]; if (t >= off) v += sc[t - off]; }
        __syncthreads();
        if (t < BUCKET) sc[t] = v;
        __syncthreads();
    }
    if (t < BUCKET) {
        int w = sc[t] - p;
        cur[t] = w;
        int node = b * BUCKET + t;
        if (node < n) {
            dinv[node] = rsqrtf((float)(cnt[t] + 1));   // +1 self-loop
            node_off[node] = b * BSTR2 + w;
            node_nq[node] = p >> 2;
        }
    }
    __syncthreads();
    // pass 2: rank into LDS
    for (int q = t; q < nq; q += 256) {
        int4v v = *(const int4v*)(bedges + base + (q << 2));
        int pos;
        pos = atomicAdd(&cur[v.x & 127], 1); sedge[pos] = v.x >> 8;
        pos = atomicAdd(&cur[v.y & 127], 1); sedge[pos] = v.y >> 8;
        pos = atomicAdd(&cur[v.z & 127], 1); sedge[pos] = v.z >> 8;
        pos = atomicAdd(&cur[v.w & 127], 1); sedge[pos] = v.w >> 8;
    }
    if (t < tail) {
        int v = bedges[base + (nq << 2) + t];
        int pos = atomicAdd(&cur[v & 127], 1); sedge[pos] = v >> 8;
    }
    __syncthreads();
    if (t < BUCKET) {
        int endc = cur[t];
        for (int i = endc; i < sc[t]; ++i) sedge[i] = n;   // sentinel -> zero row
    }
    __syncthreads();
    int total = sc[BUCKET - 1];                // multiple of 4
    int* dst2 = bedges2 + b * BSTR2;           // 16B-aligned (BSTR2*4 % 16 == 0)
    for (int j4 = t; j4 < (total >> 2); j4 += 256) {
        int4v v = *(const int4v*)(sedge + (j4 << 2));
        __builtin_nontemporal_store(v, (int4v*)(dst2 + (j4 << 2)));
    }
}

// -------- GEMM1: K-split x2, LDS-coalesced x staging, pk_fma accumulation --------
__global__ __launch_bounds__(256) void k_gemm1p(
        const float* __restrict__ x, const float* __restrict__ W,
        float* __restrict__ part, int n) {
    __shared__ float xs[RPB * LSTRIDE];        // 33792 B
    int b  = blockIdx.x >> 1;
    int ks = blockIdx.x & 1;
    int r0 = b * RPB;
    int t  = threadIdx.x;
    int r  = r0 + t;
    int kbase = ks * KHALF;

    float2v acc2[F_HID / 2];                   // float2 lanes -> v_pk_fma_f32
#pragma unroll
    for (int c = 0; c < F_HID / 2; ++c) acc2[c] = (float2v){0.0f, 0.0f};

    int lr0 = t >> 3;                           // 0..31 (stage row group)
    int c4  = t & 7;                            // 0..7  (float4 slot: 8 x 16B = 128B/row)

    for (int kc = 0; kc < KHALF; kc += KC) {
        __syncthreads();                        // xs reads of previous chunk done
#pragma unroll
        for (int j = 0; j < 8; ++j) {
            int lr = j * 32 + lr0;
            int gr = r0 + lr;
            float4v v = {0.0f, 0.0f, 0.0f, 0.0f};
            if (gr < n)
                v = *(const float4v*)(x + (size_t)gr * F_IN + kbase + kc + c4 * 4);
            float* d = xs + lr * LSTRIDE + c4 * 4;
            d[0] = v.x; d[1] = v.y; d[2] = v.z; d[3] = v.w;
        }
        __syncthreads();
        if (r < n) {
            const float* xrow = xs + t * LSTRIDE;
            const float2v* Wk2 = (const float2v*)(W + (size_t)(kbase + kc) * F_HID);
#pragma unroll
            for (int k = 0; k < KC; ++k) {
                float xv = xrow[k];
#pragma unroll
                for (int c2 = 0; c2 < F_HID / 2; ++c2)
                    acc2[c2] += xv * Wk2[k * (F_HID / 2) + c2];
            }
        }
    }
    if (r < n) {
        const float* a = (const float*)acc2;
        float4v* o = (float4v*)(part + ((size_t)ks * n + r) * F_HID);
        float4v w0 = {a[0],  a[1],  a[2],  a[3]};
        float4v w1 = {a[4],  a[5],  a[6],  a[7]};
        float4v w2 = {a[8],  a[9],  a[10], a[11]};
        float4v w3 = {a[12], a[13], a[14], a[15]};
        o[0] = w0; o[1] = w1; o[2] = w2; o[3] = w3;
    }
}

// -------- finalize GEMM1: sum K-split partials, scale by dinv, -> bf16 h1b --------
// Also zeroes sentinel row n of BOTH h1b and h2b (gathered by pad edges).
__global__ void k_fin1(const float* __restrict__ part, const float* __restrict__ dinv,
                       unsigned short* __restrict__ h1b, unsigned short* __restrict__ h2b,
                       int n) {
    int tg = blockIdx.x * 256 + threadIdx.x;
    int r = tg >> 4, c = tg & 15;
    if (r > n) return;
    if (r == n) {
        h1b[(size_t)r * F_HID + c] = 0;
        if (c < 8) h2b[((size_t)r << 3) + c] = 0;
        return;
    }
    float v = part[(size_t)r * F_HID + c] + part[((size_t)n + r) * F_HID + c];
    h1b[(size_t)r * F_HID + c] = f2bf(dinv[r] * v);
}

// ---- agg layer 1 + relu/bias + GEMM2 fused: 16 lanes/node, CSR quads, REG accumulation ----
__global__ __launch_bounds__(1024) void k_aggF1(
        const int* __restrict__ node_off, const int* __restrict__ node_nq,
        const int* __restrict__ bedges2, const unsigned short* __restrict__ h1b,
        const float* __restrict__ dinv, const float* __restrict__ b1,
        const float* __restrict__ W2, unsigned short* __restrict__ h2b, int n) {
    int tg = blockIdx.x * 1024 + threadIdx.x;
    int node = tg >> 4, c = tg & 15;
    if (node >= n) return;
    int off = node_off[node], nq = node_nq[node];
    float acc = bf2f(h1b[(size_t)node * F_HID + c]);    // self-loop (pre-scaled)
    for (int q = 0; q < nq; ++q) {
        int4v s = *(const int4v*)(bedges2 + off + (q << 2));
        float v0 = bf2f(h1b[(size_t)s.x * F_HID + c]);
        float v1 = bf2f(h1b[(size_t)s.y * F_HID + c]);
        float v2 = bf2f(h1b[(size_t)s.z * F_HID + c]);
        float v3 = bf2f(h1b[(size_t)s.w * F_HID + c]);
        acc += v0 + v1 + v2 + v3;
    }
    float dv = dinv[node];
    float z = fmaxf(dv * acc + b1[c], 0.0f);
    float h[F_OUT];
#pragma unroll
    for (int o = 0; o < F_OUT; ++o) h[o] = z * W2[c * F_OUT + o];
#pragma unroll
    for (int sft = 8; sft >= 1; sft >>= 1)
#pragma unroll
        for (int o = 0; o < F_OUT; ++o) h[o] += __shfl_xor(h[o], sft, 16);
    if (c < 8) {
        unsigned short w = (c < F_OUT) ? f2bf(dv * h[c]) : (unsigned short)0;
        h2b[((size_t)node << 3) + c] = w;
    }
}

// ------ agg layer 2 + bias fused: 8 lanes/node, CSR quads, register accumulation ------
__global__ __launch_bounds__(1024) void k_aggF2(
        const int* __restrict__ node_off, const int* __restrict__ node_nq,
        const int* __restrict__ bedges2, const unsigned short* __restrict__ h2b,
        const float* __restrict__ dinv, const float* __restrict__ b2,
        float* __restrict__ out, int n) {
    int tg = blockIdx.x * 1024 + threadIdx.x;
    int node = tg >> 3, c = tg & 7;
    if (node >= n) return;
    int off = node_off[node], nq = node_nq[node];
    float acc = bf2f(h2b[((size_t)node << 3) + c]);     // self-loop (col7 = 0)
    for (int q = 0; q < nq; ++q) {
        int4v s = *(const int4v*)(bedges2 + off + (q << 2));
        float v0 = bf2f(h2b[((size_t)s.x << 3) + c]);
        float v1 = bf2f(h2b[((size_t)s.y << 3) + c]);
        float v2 = bf2f(h2b[((size_t)s.z << 3) + c]);
        float v3 = bf2f(h2b[((size_t)s.w << 3) + c]);
        acc += v0 + v1 + v2 + v3;
    }
    if (c < F_OUT)
        out[(size_t)node * F_OUT + c] = dinv[node] * acc + b2[c];
}

extern "C" void kernel_launch(void* const* d_in, const int* in_sizes, int n_in,
                              void* d_out, int out_size, void* d_ws, size_t ws_size,
                              hipStream_t stream) {
    const float* x  = (const float*)d_in[0];
    const int*   ei = (const int*)d_in[1];      // int64 in source but JAX x64 off -> int32
    const float* W1 = (const float*)d_in[2];
    const float* b1 = (const float*)d_in[3];
    const float* W2 = (const float*)d_in[4];
    const float* b2 = (const float*)d_in[5];
    float* out = (float*)d_out;

    const int n = in_sizes[0] / F_IN;       // 100000
    const int E = in_sizes[1] / 2;          // 3200000
    const int* src = ei;
    const int* dst = ei + E;

    const int NB = (n + BUCKET - 1) / BUCKET;   // 782 (sentinel bucket NB fits < MAXNB)
    const int PBLK = (E + CHUNK - 1) / CHUNK;   // 782

    // workspace layout (16B-aligned sections)
    size_t Np = ((size_t)n + 3) & ~(size_t)3;
    char* ws = (char*)d_ws;
    int*   cursor       = (int*)ws;             ws += MAXNB * 4;
    float* dinv         = (float*)ws;           ws += Np * 4;
    int*   node_off     = (int*)ws;             ws += Np * 4;
    int*   node_nq      = (int*)ws;             ws += Np * 4;
    int*   bedges       = (int*)ws;             ws += (size_t)NB * BSTR * 4;    // 25.6 MB
    int*   bedges2      = (int*)ws;             ws += (size_t)NB * BSTR2 * 4;   // 27.2 MB
    unsigned short* h1b = (unsigned short*)ws;  ws += (Np + 4) * F_HID * 2;     // 3.2 MB
    unsigned short* h2b = (unsigned short*)ws;  ws += (Np + 4) * 8 * 2;         // 1.6 MB
    // bedges dead after k_psort; reused as fp32 GEMM1 partials (12.8 MB <= 25.6 MB)
    float* part         = (float*)bedges;

    k_init   <<<(NB + 255) / 256, 256, 0, stream>>>(cursor, NB);
    k_place4 <<<PBLK, 256, 0, stream>>>(src, dst, cursor, bedges, E, NB);
    k_psort  <<<NB, 256, 0, stream>>>(cursor, bedges, bedges2, dinv, node_off, node_nq, n);
    k_gemm1p <<<((n + RPB - 1) / RPB) * 2, 256, 0, stream>>>(x, W1, part, n);
    k_fin1   <<<((n + 1) * 16 + 255) / 256, 256, 0, stream>>>(part, dinv, h1b, h2b, n);
    k_aggF1  <<<((size_t)n * 16 + 1023) / 1024, 1024, 0, stream>>>(node_off, node_nq, bedges2, h1b, dinv, b1, W2, h2b, n);
    k_aggF2  <<<((size_t)n * 8 + 1023) / 1024, 1024, 0, stream>>>(node_off, node_nq, bedges2, h2b, dinv, b2, out, n);
}

// Round 8
// 449.716 us; speedup vs baseline: 2.0366x; 1.0265x over previous
//
#include <hip/hip_runtime.h>

#define F_IN 512
#define F_HID 16
#define F_OUT 7
#define BUCKET 128          // nodes per bucket
#define LB 7                // log2(BUCKET)
#define CHUNK 4096          // edges per partition block
#define MAXNB 1024          // max buckets supported by block-local scans
#define BSTR 8192           // bedges fixed bucket stride (mean 4092, sigma 64 -> 64-sigma safe)
#define BSTR2 8704          // bedges2 fixed stride (BSTR + 128*4 pad headroom)

// GEMM1 tiling
#define RPB 256             // rows per block
#define KC 32               // staged k-chunk
#define KHALF 256           // K range per split block (F_IN / KSPLIT)
#define LSTRIDE 33          // LDS row stride (pad: conflict-free scalar reads, 2-way writes)

typedef int   int4v   __attribute__((ext_vector_type(4)));
typedef float float2v __attribute__((ext_vector_type(2)));
typedef float float4v __attribute__((ext_vector_type(4)));
typedef unsigned int uint4v __attribute__((ext_vector_type(4)));

static __device__ __forceinline__ unsigned short f2bf(float f) {   // RNE
    unsigned int u = __float_as_uint(f);
    u += 0x7FFFu + ((u >> 16) & 1u);
    return (unsigned short)(u >> 16);
}
static __device__ __forceinline__ float bf2f(unsigned short s) {
    return __uint_as_float((unsigned int)s << 16);
}

// ---------------- init: fixed-stride bucket cursors ----------------
__global__ void k_init(int* __restrict__ cursor, int NB) {
    int i = blockIdx.x * 256 + threadIdx.x;
    if (i < NB) cursor[i] = i * BSTR;
}

// ------- place: block rank-and-reorder; global dest via per-bucket atomic cursors -------
__global__ __launch_bounds__(256) void k_place4(
        const int* __restrict__ src, const int* __restrict__ dst,
        int* __restrict__ cursor, int* __restrict__ bedges, int E, int NB) {
    __shared__ int h[MAXNB];                   // hist -> exclusive rank cursor
    __shared__ int s[MAXNB];                   // inclusive scan -> dbase
    __shared__ int sedge[CHUNK];               // 16 KB reordered packed edges
    __shared__ unsigned short sbkt[CHUNK];     // 8 KB bucket id per slot
    int t = threadIdx.x, blk = blockIdx.x;
    for (int i = t; i < MAXNB; i += 256) h[i] = 0;
    __syncthreads();
    int base = blk * CHUNK;
    int4v d4[4], s4[4];
#pragma unroll
    for (int it = 0; it < 4; ++it) {
        int e = base + (it * 256 + t) * 4;
        if (e < E) {                           // E % 4 == 0 -> whole quad valid
            d4[it] = __builtin_nontemporal_load((const int4v*)(dst + e));
            s4[it] = __builtin_nontemporal_load((const int4v*)(src + e));
        } else {
            int sent = NB << LB;               // sentinel bucket NB (skipped at write-out)
            d4[it].x = sent; d4[it].y = sent; d4[it].z = sent; d4[it].w = sent;
            s4[it].x = 0;    s4[it].y = 0;    s4[it].z = 0;    s4[it].w = 0;
        }
        atomicAdd(&h[d4[it].x >> LB], 1);
        atomicAdd(&h[d4[it].y >> LB], 1);
        atomicAdd(&h[d4[it].z >> LB], 1);
        atomicAdd(&h[d4[it].w >> LB], 1);
    }
    __syncthreads();
    for (int i = t; i < MAXNB; i += 256) s[i] = h[i];
    __syncthreads();
    // inclusive Hillis-Steele scan of s[0..1023], 256 threads x 4
    for (int off = 1; off < MAXNB; off <<= 1) {
        int v[4];
#pragma unroll
        for (int j = 0; j < 4; ++j) {
            int i = t + j * 256;
            v[j] = s[i] + ((i >= off) ? s[i - off] : 0);
        }
        __syncthreads();
#pragma unroll
        for (int j = 0; j < 4; ++j) s[t + j * 256] = v[j];
        __syncthreads();
    }
    // h := exclusive rank base; s := dbase = (atomic run reservation) - local_excl
    for (int i = t; i < MAXNB; i += 256) {
        int incl = s[i], cnt = h[i];
        int excl = incl - cnt;
        h[i] = excl;
        int db = 0;
        if (i < NB && cnt > 0)
            db = atomicAdd(&cursor[i], cnt) - excl;    // device-scope global atomic
        s[i] = db;
    }
    __syncthreads();
    // rank & reorder into LDS
#pragma unroll
    for (int it = 0; it < 4; ++it) {
        int d, sv, b, p;
        d = d4[it].x; sv = s4[it].x; b = d >> LB; p = atomicAdd(&h[b], 1);
        sedge[p] = (sv << 8) | (d & (BUCKET - 1)); sbkt[p] = (unsigned short)b;
        d = d4[it].y; sv = s4[it].y; b = d >> LB; p = atomicAdd(&h[b], 1);
        sedge[p] = (sv << 8) | (d & (BUCKET - 1)); sbkt[p] = (unsigned short)b;
        d = d4[it].z; sv = s4[it].z; b = d >> LB; p = atomicAdd(&h[b], 1);
        sedge[p] = (sv << 8) | (d & (BUCKET - 1)); sbkt[p] = (unsigned short)b;
        d = d4[it].w; sv = s4[it].w; b = d >> LB; p = atomicAdd(&h[b], 1);
        sedge[p] = (sv << 8) | (d & (BUCKET - 1)); sbkt[p] = (unsigned short)b;
    }
    __syncthreads();
    // write-out: consecutive j in a bucket run -> consecutive dest (coalesced bursts)
    for (int j = t; j < CHUNK; j += 256) {
        int b = sbkt[j];
        if (b < NB)
            __builtin_nontemporal_store(sedge[j], bedges + s[b] + j);
    }
}

// ---- psort: fused degree-count + scan + counting-sort; coalesced bedges2 write-out ----
__global__ __launch_bounds__(256) void k_psort(
        const int* __restrict__ cursor, const int* __restrict__ bedges,
        int* __restrict__ bedges2, float* __restrict__ dinv,
        int* __restrict__ node_off, int* __restrict__ node_nq, int n) {
    __shared__ int cnt[BUCKET];
    __shared__ int sc[BUCKET];                 // padded inclusive scan
    __shared__ int cur[BUCKET];
    __shared__ int sedge[BSTR2];               // 34 KB ranked srcs
    int b = blockIdx.x, t = threadIdx.x;
    int base = b * BSTR;
    int ne = cursor[b] - base;
    if (t < BUCKET) cnt[t] = 0;
    __syncthreads();
    int nq = ne >> 2, tail = ne & 3;
    for (int q = t; q < nq; q += 256) {
        int4v v = *(const int4v*)(bedges + base + (q << 2));
        atomicAdd(&cnt[v.x & 127], 1);
        atomicAdd(&cnt[v.y & 127], 1);
        atomicAdd(&cnt[v.z & 127], 1);
        atomicAdd(&cnt[v.w & 127], 1);
    }
    if (t < tail) atomicAdd(&cnt[bedges[base + (nq << 2) + t] & 127], 1);
    __syncthreads();
    int p = 0;
    if (t < BUCKET) { p = (cnt[t] + 3) & ~3; sc[t] = p; }
    __syncthreads();
    for (int off = 1; off < BUCKET; off <<= 1) {
        int v = 0;
        if (t < BUCKET) { v = sc[t]; if (t >= off) v += sc[t - off]; }
        __syncthreads();
        if (t < BUCKET) sc[t] = v;
        __syncthreads();
    }
    if (t < BUCKET) {
        int w = sc[t] - p;
        cur[t] = w;
        int node = b * BUCKET + t;
        if (node < n) {
            dinv[node] = rsqrtf((float)(cnt[t] + 1));   // +1 self-loop
            node_off[node] = b * BSTR2 + w;
            node_nq[node] = p >> 2;
        }
    }
    __syncthreads();
    // pass 2: rank into LDS
    for (int q = t; q < nq; q += 256) {
        int4v v = *(const int4v*)(bedges + base + (q << 2));
        int pos;
        pos = atomicAdd(&cur[v.x & 127], 1); sedge[pos] = v.x >> 8;
        pos = atomicAdd(&cur[v.y & 127], 1); sedge[pos] = v.y >> 8;
        pos = atomicAdd(&cur[v.z & 127], 1); sedge[pos] = v.z >> 8;
        pos = atomicAdd(&cur[v.w & 127], 1); sedge[pos] = v.w >> 8;
    }
    if (t < tail) {
        int v = bedges[base + (nq << 2) + t];
        int pos = atomicAdd(&cur[v & 127], 1); sedge[pos] = v >> 8;
    }
    __syncthreads();
    if (t < BUCKET) {
        int endc = cur[t];
        for (int i = endc; i < sc[t]; ++i) sedge[i] = n;   // sentinel -> zero row
    }
    __syncthreads();
    int total = sc[BUCKET - 1];                // multiple of 4
    int* dst2 = bedges2 + b * BSTR2;           // 16B-aligned (BSTR2*4 % 16 == 0)
    for (int j4 = t; j4 < (total >> 2); j4 += 256) {
        int4v v = *(const int4v*)(sedge + (j4 << 2));
        __builtin_nontemporal_store(v, (int4v*)(dst2 + (j4 << 2)));
    }
}

// -------- GEMM1: K-split x2, software-pipelined LDS staging (register prefetch) --------
// Per chunk: {barrier; store prefetched regs -> LDS; barrier; issue next chunk's 8
// global loads; compute current chunk}. Load latency hides under compute; only the
// LDS-store drain is exposed at the barrier (fix for the vmcnt(0)-per-chunk stall).
__global__ __launch_bounds__(256) void k_gemm1p(
        const float* __restrict__ x, const float* __restrict__ W,
        float* __restrict__ part, int n) {
    __shared__ float xs[RPB * LSTRIDE];        // 33792 B
    int b  = blockIdx.x >> 1;
    int ks = blockIdx.x & 1;
    int r0 = b * RPB;
    int t  = threadIdx.x;
    int r  = r0 + t;
    int kbase = ks * KHALF;

    float2v acc2[F_HID / 2];                   // float2 lanes -> v_pk_fma_f32
#pragma unroll
    for (int c = 0; c < F_HID / 2; ++c) acc2[c] = (float2v){0.0f, 0.0f};

    int lr0 = t >> 3;                           // 0..31 (stage row group)
    int c4  = t & 7;                            // 0..7  (float4 slot: 8 x 16B = 128B/row)

    float4v pv[8];                              // prefetch registers (one chunk)
#pragma unroll
    for (int j = 0; j < 8; ++j) {
        int gr = r0 + j * 32 + lr0;
        float4v v = {0.0f, 0.0f, 0.0f, 0.0f};
        if (gr < n)
            v = *(const float4v*)(x + (size_t)gr * F_IN + kbase + c4 * 4);
        pv[j] = v;
    }

    for (int kc = 0; kc < KHALF; kc += KC) {
        __syncthreads();                        // xs reads of previous chunk done
#pragma unroll
        for (int j = 0; j < 8; ++j) {
            float* d = xs + (j * 32 + lr0) * LSTRIDE + c4 * 4;
            d[0] = pv[j].x; d[1] = pv[j].y; d[2] = pv[j].z; d[3] = pv[j].w;
        }
        __syncthreads();                        // xs ready
        if (kc + KC < KHALF) {                  // issue next chunk's loads (async)
#pragma unroll
            for (int j = 0; j < 8; ++j) {
                int gr = r0 + j * 32 + lr0;
                float4v v = {0.0f, 0.0f, 0.0f, 0.0f};
                if (gr < n)
                    v = *(const float4v*)(x + (size_t)gr * F_IN + kbase + kc + KC + c4 * 4);
                pv[j] = v;
            }
        }
        if (r < n) {
            const float* xrow = xs + t * LSTRIDE;
            const float2v* Wk2 = (const float2v*)(W + (size_t)(kbase + kc) * F_HID);
#pragma unroll
            for (int k = 0; k < KC; ++k) {
                float xv = xrow[k];
#pragma unroll
                for (int c2 = 0; c2 < F_HID / 2; ++c2)
                    acc2[c2] += xv * Wk2[k * (F_HID / 2) + c2];
            }
        }
    }
    if (r < n) {
        const float* a = (const float*)acc2;
        float4v* o = (float4v*)(part + ((size_t)ks * n + r) * F_HID);
        float4v w0 = {a[0],  a[1],  a[2],  a[3]};
        float4v w1 = {a[4],  a[5],  a[6],  a[7]};
        float4v w2 = {a[8],  a[9],  a[10], a[11]};
        float4v w3 = {a[12], a[13], a[14], a[15]};
        o[0] = w0; o[1] = w1; o[2] = w2; o[3] = w3;
    }
}

// -------- finalize GEMM1: sum K-split partials, scale by dinv, -> bf16 h1b --------
// Also zeroes sentinel row n of BOTH h1b and h2b (gathered by pad edges).
__global__ void k_fin1(const float* __restrict__ part, const float* __restrict__ dinv,
                       unsigned short* __restrict__ h1b, unsigned short* __restrict__ h2b,
                       int n) {
    int tg = blockIdx.x * 256 + threadIdx.x;
    int r = tg >> 4, c = tg & 15;
    if (r > n) return;
    if (r == n) {
        h1b[(size_t)r * F_HID + c] = 0;
        if (c < 8) h2b[((size_t)r << 3) + c] = 0;
        return;
    }
    float v = part[(size_t)r * F_HID + c] + part[((size_t)n + r) * F_HID + c];
    h1b[(size_t)r * F_HID + c] = f2bf(dinv[r] * v);
}

// ---- agg layer 1 + relu/bias + GEMM2 fused: 16 lanes/node, CSR quads, REG accumulation ----
__global__ __launch_bounds__(1024) void k_aggF1(
        const int* __restrict__ node_off, const int* __restrict__ node_nq,
        const int* __restrict__ bedges2, const unsigned short* __restrict__ h1b,
        const float* __restrict__ dinv, const float* __restrict__ b1,
        const float* __restrict__ W2, unsigned short* __restrict__ h2b, int n) {
    int tg = blockIdx.x * 1024 + threadIdx.x;
    int node = tg >> 4, c = tg & 15;
    if (node >= n) return;
    int off = node_off[node], nq = node_nq[node];
    float acc = bf2f(h1b[(size_t)node * F_HID + c]);    // self-loop (pre-scaled)
    for (int q = 0; q < nq; ++q) {
        int4v s = *(const int4v*)(bedges2 + off + (q << 2));
        float v0 = bf2f(h1b[(size_t)s.x * F_HID + c]);
        float v1 = bf2f(h1b[(size_t)s.y * F_HID + c]);
        float v2 = bf2f(h1b[(size_t)s.z * F_HID + c]);
        float v3 = bf2f(h1b[(size_t)s.w * F_HID + c]);
        acc += v0 + v1 + v2 + v3;
    }
    float dv = dinv[node];
    float z = fmaxf(dv * acc + b1[c], 0.0f);
    float h[F_OUT];
#pragma unroll
    for (int o = 0; o < F_OUT; ++o) h[o] = z * W2[c * F_OUT + o];
#pragma unroll
    for (int sft = 8; sft >= 1; sft >>= 1)
#pragma unroll
        for (int o = 0; o < F_OUT; ++o) h[o] += __shfl_xor(h[o], sft, 16);
    if (c < 8) {
        unsigned short w = (c < F_OUT) ? f2bf(dv * h[c]) : (unsigned short)0;
        h2b[((size_t)node << 3) + c] = w;
    }
}

// ------ agg layer 2 + bias fused: 8 lanes/node, CSR quads, register accumulation ------
__global__ __launch_bounds__(1024) void k_aggF2(
        const int* __restrict__ node_off, const int* __restrict__ node_nq,
        const int* __restrict__ bedges2, const unsigned short* __restrict__ h2b,
        const float* __restrict__ dinv, const float* __restrict__ b2,
        float* __restrict__ out, int n) {
    int tg = blockIdx.x * 1024 + threadIdx.x;
    int node = tg >> 3, c = tg & 7;
    if (node >= n) return;
    int off = node_off[node], nq = node_nq[node];
    float acc = bf2f(h2b[((size_t)node << 3) + c]);     // self-loop (col7 = 0)
    for (int q = 0; q < nq; ++q) {
        int4v s = *(const int4v*)(bedges2 + off + (q << 2));
        float v0 = bf2f(h2b[((size_t)s.x << 3) + c]);
        float v1 = bf2f(h2b[((size_t)s.y << 3) + c]);
        float v2 = bf2f(h2b[((size_t)s.z << 3) + c]);
        float v3 = bf2f(h2b[((size_t)s.w << 3) + c]);
        acc += v0 + v1 + v2 + v3;
    }
    if (c < F_OUT)
        out[(size_t)node * F_OUT + c] = dinv[node] * acc + b2[c];
}

extern "C" void kernel_launch(void* const* d_in, const int* in_sizes, int n_in,
                              void* d_out, int out_size, void* d_ws, size_t ws_size,
                              hipStream_t stream) {
    const float* x  = (const float*)d_in[0];
    const int*   ei = (const int*)d_in[1];      // int64 in source but JAX x64 off -> int32
    const float* W1 = (const float*)d_in[2];
    const float* b1 = (const float*)d_in[3];
    const float* W2 = (const float*)d_in[4];
    const float* b2 = (const float*)d_in[5];
    float* out = (float*)d_out;

    const int n = in_sizes[0] / F_IN;       // 100000
    const int E = in_sizes[1] / 2;          // 3200000
    const int* src = ei;
    const int* dst = ei + E;

    const int NB = (n + BUCKET - 1) / BUCKET;   // 782 (sentinel bucket NB fits < MAXNB)
    const int PBLK = (E + CHUNK - 1) / CHUNK;   // 782

    // workspace layout (16B-aligned sections)
    size_t Np = ((size_t)n + 3) & ~(size_t)3;
    char* ws = (char*)d_ws;
    int*   cursor       = (int*)ws;             ws += MAXNB * 4;
    float* dinv         = (float*)ws;           ws += Np * 4;
    int*   node_off     = (int*)ws;             ws += Np * 4;
    int*   node_nq      = (int*)ws;             ws += Np * 4;
    int*   bedges       = (int*)ws;             ws += (size_t)NB * BSTR * 4;    // 25.6 MB
    int*   bedges2      = (int*)ws;             ws += (size_t)NB * BSTR2 * 4;   // 27.2 MB
    unsigned short* h1b = (unsigned short*)ws;  ws += (Np + 4) * F_HID * 2;     // 3.2 MB
    unsigned short* h2b = (unsigned short*)ws;  ws += (Np + 4) * 8 * 2;         // 1.6 MB
    // bedges dead after k_psort; reused as fp32 GEMM1 partials (12.8 MB <= 25.6 MB)
    float* part         = (float*)bedges;

    k_init   <<<(NB + 255) / 256, 256, 0, stream>>>(cursor, NB);
    k_place4 <<<PBLK, 256, 0, stream>>>(src, dst, cursor, bedges, E, NB);
    k_psort  <<<NB, 256, 0, stream>>>(cursor, bedges, bedges2, dinv, node_off, node_nq, n);
    k_gemm1p <<<((n + RPB - 1) / RPB) * 2, 256, 0, stream>>>(x, W1, part, n);
    k_fin1   <<<((n + 1) * 16 + 255) / 256, 256, 0, stream>>>(part, dinv, h1b, h2b, n);
    k_aggF1  <<<((size_t)n * 16 + 1023) / 1024, 1024, 0, stream>>>(node_off, node_nq, bedges2, h1b, dinv, b1, W2, h2b, n);
    k_aggF2  <<<((size_t)n * 8 + 1023) / 1024, 1024, 0, stream>>>(node_off, node_nq, bedges2, h2b, dinv, b2, out, n);
}